// Round 1
// baseline (25177.975 us; speedup 1.0000x reference)
//
#include <hip/hip_runtime.h>
#include <hip/hip_bf16.h>
#include <cstdint>
#include <cstddef>

// Problem constants (from reference)
#define T_SEQ   512
#define BATCH   8
#define BT      4096        // BATCH*T_SEQ
#define DMODEL  1024
#define NHEAD   16
#define HSZ     64
#define NLAYER  8
#define DFF     4096
#define VOCAB   32000
#define EPS     1e-6f
#define NEG_SLOPE 0.1f

// ---------------------------------------------------------------------------
// embed: x[bt,d] = tok_embed[idx[bt],d] + pos_embed[bt%T, d]
// grid: BT blocks x 256 threads (4 floats/thread via float4)
__global__ void embed_kernel(const int* __restrict__ idx,
                             const float* __restrict__ tok,
                             const float* __restrict__ pos,
                             float* __restrict__ x) {
    int bt  = blockIdx.x;
    int tid = threadIdx.x;
    int token = idx[bt];
    int t = bt & (T_SEQ - 1);
    float4 a = reinterpret_cast<const float4*>(tok + (size_t)token * DMODEL)[tid];
    float4 p = reinterpret_cast<const float4*>(pos + (size_t)t * DMODEL)[tid];
    float4 o = make_float4(a.x + p.x, a.y + p.y, a.z + p.z, a.w + p.w);
    reinterpret_cast<float4*>(x + (size_t)bt * DMODEL)[tid] = o;
}

// ---------------------------------------------------------------------------
// rmsnorm: out = x * rsqrt(mean(x^2)+eps) * w     (one block of 256 per row)
__global__ void rmsnorm_kernel(const float* __restrict__ x,
                               const float* __restrict__ w,
                               float* __restrict__ out) {
    int row = blockIdx.x;
    int tid = threadIdx.x;
    float4 v = reinterpret_cast<const float4*>(x + (size_t)row * DMODEL)[tid];
    float ss = v.x * v.x + v.y * v.y + v.z * v.z + v.w * v.w;
#pragma unroll
    for (int off = 32; off > 0; off >>= 1) ss += __shfl_xor(ss, off);
    __shared__ float wsum[4];
    if ((tid & 63) == 0) wsum[tid >> 6] = ss;
    __syncthreads();
    float tot = wsum[0] + wsum[1] + wsum[2] + wsum[3];
    float scale = rsqrtf(tot * (1.0f / DMODEL) + EPS);
    float4 wv = reinterpret_cast<const float4*>(w)[tid];
    float4 o = make_float4(v.x * scale * wv.x, v.y * scale * wv.y,
                           v.z * scale * wv.z, v.w * scale * wv.w);
    reinterpret_cast<float4*>(out + (size_t)row * DMODEL)[tid] = o;
}

// ---------------------------------------------------------------------------
// Generic f32 GEMM: C[M,N] = act(A[M,K] @ W + bias) (+resid)
// W element (k,n) at  W[k*sK + (n>>6)*sH + (n&63)]:
//   row-major (K,N):          sK=N,   sH=64
//   head-major (H,D,HS=64):   sK=64,  sH=D*64   (n = h*64+e)
// 128x128 tile, K-step 16, 256 threads, 8x8 per thread.
template <bool LRELU>
__global__ __launch_bounds__(256)
void gemm128(const float* __restrict__ A, const float* __restrict__ W,
             const float* __restrict__ bias, const float* __restrict__ resid,
             float* __restrict__ C, int M, int N, int K, int sK, int sH) {
    __shared__ float As[16][128];   // [k][m]
    __shared__ float Bs[16][128];   // [k][n]
    int tid = threadIdx.x;
    int tx = tid & 15, ty = tid >> 4;
    int m0 = blockIdx.y << 7, n0 = blockIdx.x << 7;

    float acc[8][8];
#pragma unroll
    for (int i = 0; i < 8; ++i)
#pragma unroll
        for (int j = 0; j < 8; ++j) acc[i][j] = 0.f;

    int arow = tid >> 2, acol = (tid & 3) << 2;   // A tile: 128 rows x 16 k
    int bk = tid >> 5, bn = (tid & 31) << 2;      // B tile: 16 k x 128 n

    for (int k0 = 0; k0 < K; k0 += 16) {
#pragma unroll
        for (int r = 0; r < 2; ++r) {
            int row = arow + (r << 6);
            float4 a4 = *reinterpret_cast<const float4*>(
                A + (size_t)(m0 + row) * K + k0 + acol);
            As[acol + 0][row] = a4.x;
            As[acol + 1][row] = a4.y;
            As[acol + 2][row] = a4.z;
            As[acol + 3][row] = a4.w;
        }
#pragma unroll
        for (int r = 0; r < 2; ++r) {
            int kk = bk + (r << 3);
            int n = n0 + bn;
            const float* wp = W + (size_t)(k0 + kk) * sK +
                              (size_t)(n >> 6) * sH + (n & 63);
            *reinterpret_cast<float4*>(&Bs[kk][bn]) =
                *reinterpret_cast<const float4*>(wp);
        }
        __syncthreads();
#pragma unroll
        for (int kk = 0; kk < 16; ++kk) {
            float a[8], b[8];
#pragma unroll
            for (int i = 0; i < 8; ++i) a[i] = As[kk][(ty << 3) + i];
#pragma unroll
            for (int j = 0; j < 8; ++j) b[j] = Bs[kk][(tx << 3) + j];
#pragma unroll
            for (int i = 0; i < 8; ++i)
#pragma unroll
                for (int j = 0; j < 8; ++j) acc[i][j] += a[i] * b[j];
        }
        __syncthreads();
    }
#pragma unroll
    for (int i = 0; i < 8; ++i) {
        int m = m0 + (ty << 3) + i;
#pragma unroll
        for (int j = 0; j < 8; ++j) {
            int n = n0 + (tx << 3) + j;
            float v = acc[i][j] + bias[n];
            if (LRELU) v = (v >= 0.f) ? v : NEG_SLOPE * v;
            if (resid) v += resid[(size_t)m * N + n];
            C[(size_t)m * N + n] = v;
        }
    }
}

// ---------------------------------------------------------------------------
// scores[bh,t,s] = sqrt(HS) * sum_e q[b,t,h,e]*k[b,s,h,e]
// q/k stored (BT, D) row-major, head columns h*64+e.
// grid: (T/64, T/64, B*H); 256 threads; 64x64 tile, 4x4/thread, K=64 in LDS.
__global__ __launch_bounds__(256)
void attn_scores_kernel(const float* __restrict__ q, const float* __restrict__ k,
                        float* __restrict__ sc) {
    int bh = blockIdx.z;
    int b = bh >> 4, h = bh & 15;
    int t0 = blockIdx.y << 6, s0 = blockIdx.x << 6;
    __shared__ float Qs[64][68];
    __shared__ float Ks[64][68];
    int tid = threadIdx.x;
    int tx = tid & 15, ty = tid >> 4;
    int lr = tid >> 4, le = (tid & 15) << 2;
#pragma unroll
    for (int r = 0; r < 4; ++r) {
        int row = lr + (r << 4);
        float4 qv = *reinterpret_cast<const float4*>(
            q + (size_t)(b * T_SEQ + t0 + row) * DMODEL + h * HSZ + le);
        *reinterpret_cast<float4*>(&Qs[row][le]) = qv;
        float4 kv = *reinterpret_cast<const float4*>(
            k + (size_t)(b * T_SEQ + s0 + row) * DMODEL + h * HSZ + le);
        *reinterpret_cast<float4*>(&Ks[row][le]) = kv;
    }
    __syncthreads();
    float acc[4][4] = {};
#pragma unroll 4
    for (int e = 0; e < 64; ++e) {
        float a[4], bb[4];
#pragma unroll
        for (int i = 0; i < 4; ++i) a[i] = Qs[(ty << 2) + i][e];
#pragma unroll
        for (int j = 0; j < 4; ++j) bb[j] = Ks[(tx << 2) + j][e];
#pragma unroll
        for (int i = 0; i < 4; ++i)
#pragma unroll
            for (int j = 0; j < 4; ++j) acc[i][j] += a[i] * bb[j];
    }
#pragma unroll
    for (int i = 0; i < 4; ++i) {
        size_t rbase = ((size_t)bh * T_SEQ + t0 + (ty << 2) + i) * T_SEQ;
#pragma unroll
        for (int j = 0; j < 4; ++j)
            sc[rbase + s0 + (tx << 2) + j] = 8.0f * acc[i][j];
    }
}

// ---------------------------------------------------------------------------
// row softmax (optionally causal). One wave (64) per row of 512.
__global__ void softmax_kernel(float* __restrict__ sc, int causal) {
    size_t row = blockIdx.x;            // bh*T + t
    int t = (int)(row & (T_SEQ - 1));
    float* p = sc + row * T_SEQ;
    int lane = threadIdx.x;
    float vbuf[8];
    float mx = -INFINITY;
#pragma unroll
    for (int j = 0; j < 8; ++j) {
        int s = lane + (j << 6);
        float val = p[s];
        if (causal && s > t) val = -INFINITY;
        vbuf[j] = val;
        mx = fmaxf(mx, val);
    }
#pragma unroll
    for (int off = 32; off > 0; off >>= 1) mx = fmaxf(mx, __shfl_xor(mx, off));
    float sum = 0.f;
#pragma unroll
    for (int j = 0; j < 8; ++j) {
        float e = expf(vbuf[j] - mx);
        vbuf[j] = e;
        sum += e;
    }
#pragma unroll
    for (int off = 32; off > 0; off >>= 1) sum += __shfl_xor(sum, off);
    float inv = 1.f / sum;
#pragma unroll
    for (int j = 0; j < 8; ++j) p[lane + (j << 6)] = vbuf[j] * inv;
}

// ---------------------------------------------------------------------------
// out[b,t, h*64+e] = sum_s att[bh,t,s] * v[b,s,h,e]
// grid: (T/64, B*H); 256 threads; 64(t) x 64(e) tile, K-step 16 over s.
__global__ __launch_bounds__(256)
void attn_av_kernel(const float* __restrict__ att, const float* __restrict__ v,
                    float* __restrict__ out) {
    int bh = blockIdx.y;
    int b = bh >> 4, h = bh & 15;
    int t0 = blockIdx.x << 6;
    __shared__ float As[64][20];    // att[t][s-chunk]
    __shared__ float Vs[16][64];    // v[s-chunk][e]
    int tid = threadIdx.x;
    int tx = tid & 15, ty = tid >> 4;
    int at_row = tid >> 2, at_col = (tid & 3) << 2;
    int v_row = tid >> 4, v_col = (tid & 15) << 2;
    float acc[4][4] = {};
    for (int s0 = 0; s0 < T_SEQ; s0 += 16) {
        float4 a4 = *reinterpret_cast<const float4*>(
            att + ((size_t)bh * T_SEQ + t0 + at_row) * T_SEQ + s0 + at_col);
        *reinterpret_cast<float4*>(&As[at_row][at_col]) = a4;
        float4 v4 = *reinterpret_cast<const float4*>(
            v + (size_t)(b * T_SEQ + s0 + v_row) * DMODEL + h * HSZ + v_col);
        *reinterpret_cast<float4*>(&Vs[v_row][v_col]) = v4;
        __syncthreads();
#pragma unroll
        for (int kk = 0; kk < 16; ++kk) {
            float a[4], bb[4];
#pragma unroll
            for (int i = 0; i < 4; ++i) a[i] = As[(ty << 2) + i][kk];
#pragma unroll
            for (int j = 0; j < 4; ++j) bb[j] = Vs[kk][(tx << 2) + j];
#pragma unroll
            for (int i = 0; i < 4; ++i)
#pragma unroll
                for (int j = 0; j < 4; ++j) acc[i][j] += a[i] * bb[j];
        }
        __syncthreads();
    }
#pragma unroll
    for (int i = 0; i < 4; ++i) {
        size_t obase = (size_t)(b * T_SEQ + t0 + (ty << 2) + i) * DMODEL + h * HSZ;
#pragma unroll
        for (int j = 0; j < 4; ++j) out[obase + (tx << 2) + j] = acc[i][j];
    }
}

// ---------------------------------------------------------------------------
extern "C" void kernel_launch(void* const* d_in, const int* in_sizes, int n_in,
                              void* d_out, int out_size, void* d_ws, size_t ws_size,
                              hipStream_t stream) {
    const int*   idx = (const int*)  d_in[0];
    const float* tok = (const float*)d_in[1];
    const float* pos = (const float*)d_in[2];
    const float* Wq  = (const float*)d_in[3];
    const float* bq  = (const float*)d_in[4];
    const float* Wk  = (const float*)d_in[5];
    const float* bk  = (const float*)d_in[6];
    const float* Wv  = (const float*)d_in[7];
    const float* bv  = (const float*)d_in[8];
    const float* Wo  = (const float*)d_in[9];
    const float* bo  = (const float*)d_in[10];
    const float* W1  = (const float*)d_in[11];
    const float* b1  = (const float*)d_in[12];
    const float* W2  = (const float*)d_in[13];
    const float* b2  = (const float*)d_in[14];
    const float* nw  = (const float*)d_in[15];
    const float* fnw = (const float*)d_in[16];
    const float* Wf  = (const float*)d_in[17];
    const float* bf  = (const float*)d_in[18];
    float* out = (float*)d_out;

    const size_t SZ = (size_t)BT * DMODEL;   // 4M floats
    float* ws = (float*)d_ws;
    float* x  = ws;
    float* xo = x  + SZ;
    float* xn = xo + SZ;
    float* q  = xn + SZ;
    float* kb = q  + SZ;
    float* vb = kb + SZ;
    float* ao = vb + SZ;
    // FFN hidden (16M floats) and attention scores (33.5M floats) are never
    // live simultaneously -> union them.
    float* hb = ao + SZ;
    float* sc = hb;

    const size_t WQKV = (size_t)NHEAD * DMODEL * HSZ;   // per-layer per-proj

    auto gemm = [&](const float* A, const float* W, const float* bias,
                    const float* resid, float* C, int M, int N, int K,
                    int sK, int sH, bool lrelu) {
        dim3 grid(N >> 7, M >> 7);
        if (lrelu)
            gemm128<true><<<grid, 256, 0, stream>>>(A, W, bias, resid, C, M, N, K, sK, sH);
        else
            gemm128<false><<<grid, 256, 0, stream>>>(A, W, bias, resid, C, M, N, K, sK, sH);
    };

    embed_kernel<<<BT, 256, 0, stream>>>(idx, tok, pos, x);

    for (int l = 0; l < NLAYER; ++l) {
        const float* nwl = nw + (size_t)l * DMODEL;
        const float* Wql = Wq + (size_t)l * WQKV;
        const float* Wkl = Wk + (size_t)l * WQKV;
        const float* Wvl = Wv + (size_t)l * WQKV;
        const float* bql = bq + (size_t)l * DMODEL;
        const float* bkl = bk + (size_t)l * DMODEL;
        const float* bvl = bv + (size_t)l * DMODEL;
        const float* Wol = Wo + (size_t)l * DMODEL * DMODEL;
        const float* bol = bo + (size_t)l * DMODEL;
        const float* W1l = W1 + (size_t)l * DMODEL * DFF;
        const float* b1l = b1 + (size_t)l * DFF;
        const float* W2l = W2 + (size_t)l * DFF * DMODEL;
        const float* b2l = b2 + (size_t)l * DMODEL;

        auto attn = [&](const float* xin, const float* resid, float* outp, int causal) {
            // per-head QKV: W layout (H, D, HS) -> sK=HSZ, sH=D*HSZ
            gemm(xin, Wql, bql, nullptr, q,  BT, DMODEL, DMODEL, HSZ, DMODEL * HSZ, false);
            gemm(xin, Wkl, bkl, nullptr, kb, BT, DMODEL, DMODEL, HSZ, DMODEL * HSZ, false);
            gemm(xin, Wvl, bvl, nullptr, vb, BT, DMODEL, DMODEL, HSZ, DMODEL * HSZ, false);
            attn_scores_kernel<<<dim3(T_SEQ / 64, T_SEQ / 64, BATCH * NHEAD), 256, 0, stream>>>(q, kb, sc);
            softmax_kernel<<<BATCH * NHEAD * T_SEQ, 64, 0, stream>>>(sc, causal);
            attn_av_kernel<<<dim3(T_SEQ / 64, BATCH * NHEAD), 256, 0, stream>>>(sc, vb, ao);
            gemm(ao, Wol, bol, resid, outp, BT, DMODEL, DMODEL, DMODEL, HSZ, false);
        };

        // x_out = x + attn(rms(x), unmasked)
        rmsnorm_kernel<<<BT, 256, 0, stream>>>(x, nwl, xn);
        attn(xn, x, xo, 0);
        // x_out = x + ffn(rms(x_out))           (residual from ORIGINAL x)
        rmsnorm_kernel<<<BT, 256, 0, stream>>>(xo, nwl, xn);
        gemm(xn, W1l, b1l, nullptr, hb, BT, DFF, DMODEL, DFF, HSZ, true);
        gemm(hb, W2l, b2l, x, xo, BT, DMODEL, DFF, DMODEL, HSZ, false);
        // x = x_out + attn(rms(x_out), masked)
        rmsnorm_kernel<<<BT, 256, 0, stream>>>(xo, nwl, xn);
        attn(xn, xo, x, 1);
    }

    rmsnorm_kernel<<<BT, 256, 0, stream>>>(x, fnw, xn);
    gemm(xn, Wf, bf, nullptr, out, BT, VOCAB, DMODEL, VOCAB, HSZ, false);
}

// Round 3
// 17736.685 us; speedup vs baseline: 1.4195x; 1.4195x over previous
//
#include <hip/hip_runtime.h>
#include <hip/hip_bf16.h>
#include <cstdint>
#include <cstddef>

#define T_SEQ   512
#define BATCH   8
#define BT      4096
#define DMODEL  1024
#define NHEAD   16
#define HSZ     64
#define NLAYER  8
#define DFF     4096
#define VOCAB   32000
#define EPS     1e-6f
#define NEG_SLOPE 0.1f
#define QLD     3072    // fused qkv row stride

typedef __attribute__((ext_vector_type(8))) short short8;
typedef __attribute__((ext_vector_type(4))) float f32x4;
typedef __hip_bfloat16 bf16;

#define AS1 __attribute__((address_space(1)))
#define AS3 __attribute__((address_space(3)))

// ---------------------------------------------------------------------------
// embed: x[bt,d] = tok[idx[bt],d] + pos[bt%T,d]   (f32)
__global__ void embed_kernel(const int* __restrict__ idx,
                             const float* __restrict__ tok,
                             const float* __restrict__ pos,
                             float* __restrict__ x) {
    int bt  = blockIdx.x;
    int tid = threadIdx.x;
    int token = idx[bt];
    int t = bt & (T_SEQ - 1);
    float4 a = reinterpret_cast<const float4*>(tok + (size_t)token * DMODEL)[tid];
    float4 p = reinterpret_cast<const float4*>(pos + (size_t)t * DMODEL)[tid];
    reinterpret_cast<float4*>(x + (size_t)bt * DMODEL)[tid] =
        make_float4(a.x + p.x, a.y + p.y, a.z + p.z, a.w + p.w);
}

// ---------------------------------------------------------------------------
// exact 3-way bf16 split of an f32 value (x == h + m + l exactly)
__device__ __forceinline__ void split3v(float v, bf16& h, bf16& m, bf16& l) {
    h = __float2bfloat16(v);
    float r1 = v - __bfloat162float(h);
    m = __float2bfloat16(r1);
    float r2 = r1 - __bfloat162float(m);
    l = __float2bfloat16(r2);
}

// ---------------------------------------------------------------------------
// rmsnorm f32 -> 3 bf16 planes (plane stride = planeStride elements)
__global__ void rms_split(const float* __restrict__ x,
                          const float* __restrict__ w,
                          bf16* __restrict__ out, size_t planeStride) {
    int row = blockIdx.x;
    int tid = threadIdx.x;
    float4 v = reinterpret_cast<const float4*>(x + (size_t)row * DMODEL)[tid];
    float ss = v.x * v.x + v.y * v.y + v.z * v.z + v.w * v.w;
#pragma unroll
    for (int off = 32; off > 0; off >>= 1) ss += __shfl_xor(ss, off);
    __shared__ float wsum[4];
    if ((tid & 63) == 0) wsum[tid >> 6] = ss;
    __syncthreads();
    float tot = wsum[0] + wsum[1] + wsum[2] + wsum[3];
    float scale = rsqrtf(tot * (1.0f / DMODEL) + EPS);
    float4 wv = reinterpret_cast<const float4*>(w)[tid];
    float o[4] = {v.x * scale * wv.x, v.y * scale * wv.y,
                  v.z * scale * wv.z, v.w * scale * wv.w};
    size_t base = (size_t)row * DMODEL + tid * 4;
#pragma unroll
    for (int j = 0; j < 4; ++j) {
        bf16 h, m, l;
        split3v(o[j], h, m, l);
        out[base + j] = h;
        out[planeStride + base + j] = m;
        out[2 * planeStride + base + j] = l;
    }
}

// ---------------------------------------------------------------------------
// elementwise f32 -> 3 bf16 planes (for attn output / ffn hidden)
__global__ void split3_kernel(const float* __restrict__ in, bf16* __restrict__ out,
                              size_t planeStride, size_t n4) {
    size_t i = (size_t)blockIdx.x * 256 + threadIdx.x;
    size_t stride = (size_t)gridDim.x * 256;
    for (; i < n4; i += stride) {
        float4 v = reinterpret_cast<const float4*>(in)[i];
        float a[4] = {v.x, v.y, v.z, v.w};
        size_t base = i * 4;
#pragma unroll
        for (int j = 0; j < 4; ++j) {
            bf16 h, m, l;
            split3v(a[j], h, m, l);
            out[base + j] = h;
            out[planeStride + base + j] = m;
            out[2 * planeStride + base + j] = l;
        }
    }
}

// ---------------------------------------------------------------------------
// Tiled transpose + 3-way split: in (R,C) f32 -> out (C,R) bf16 x nPlanes.
// batch z: in += z*izs ; out += z*ozi
__global__ __launch_bounds__(256)
void transpose_split(const float* __restrict__ in, bf16* __restrict__ out,
                     size_t planeStride, int nPlanes, int R, int C,
                     long izs, long ozi) {
    int z = blockIdx.z;
    in  += (size_t)z * izs;
    out += (size_t)z * ozi;
    __shared__ float tile[32][33];
    int r0 = blockIdx.y << 5, c0 = blockIdx.x << 5;
    int tx = threadIdx.x & 31, ty = threadIdx.x >> 5;
#pragma unroll
    for (int i = 0; i < 4; ++i) {
        int r = ty + (i << 3);
        tile[r][tx] = in[(size_t)(r0 + r) * C + c0 + tx];
    }
    __syncthreads();
#pragma unroll
    for (int i = 0; i < 4; ++i) {
        int c = ty + (i << 3);
        float v = tile[tx][c];
        size_t o = (size_t)(c0 + c) * R + r0 + tx;
        bf16 h = __float2bfloat16(v);
        out[o] = h;
        if (nPlanes > 1) {
            float r1 = v - __bfloat162float(h);
            bf16 m = __float2bfloat16(r1);
            out[planeStride + o] = m;
            if (nPlanes > 2) {
                float r2 = r1 - __bfloat162float(m);
                out[2 * planeStride + o] = __float2bfloat16(r2);
            }
        }
    }
}

// concat per-layer qkv bias into (L, 3072) f32
__global__ void cat_bias(const float* __restrict__ bq, const float* __restrict__ bk,
                         const float* __restrict__ bv, float* __restrict__ cb) {
    int i = blockIdx.x * 256 + threadIdx.x;     // < L*3072
    int l = i / QLD, r = i - l * QLD;
    const float* src = (r < 1024) ? bq : ((r < 2048) ? bk : bv);
    cb[i] = src[l * 1024 + (r & 1023)];
}

// ---------------------------------------------------------------------------
// Split-precision MFMA GEMM: C = sum_p A[PA[p]] @ B[PB[p]]^T  (+bias,lrelu,resid)
// A planes: M x K bf16, stride aPS. B planes: N x K bf16 (pre-transposed), bPS.
// NP=6: full f32-grade (pairs mm, hl, lh, hm, mh, hh — smallest first).
// NP=3: pairs hm, mh, hh (for the final vocab GEMM; error ~2^-18).
// m97 structure: 128x128 tile, BK=32, 4 waves, 16x16x32 MFMA, global_load_lds.
template <int NP, bool LRELU>
__global__ __launch_bounds__(256)
void gemm_split(const bf16* __restrict__ A, size_t aPS,
                const bf16* __restrict__ Bt, size_t bPS,
                const float* __restrict__ bias,
                const float* __restrict__ resid,
                float* __restrict__ C, int M, int N, int K) {
    constexpr int PA[6] = {1, 0, 2, 0, 1, 0};
    constexpr int PB[6] = {1, 2, 0, 1, 0, 0};
    __shared__ bf16 As[128 * 32];   // [row][k], 64B rows
    __shared__ bf16 Bs[128 * 32];
    const int tid  = threadIdx.x;
    const int lane = tid & 63;
    const int wid  = tid >> 6;
    const int m0 = blockIdx.y << 7;
    const int n0 = blockIdx.x << 7;

    // staging: chunk c (0..7) = rows [c*16,c*16+16); lane -> row c*16+(lane>>2),
    // k-offset (lane&3)*8; HW writes LDS at chunk base + lane*16B (linear).
    const int srow = lane >> 2;
    const int skc  = (lane & 3) << 3;
    size_t offA[2], offB[2];
#pragma unroll
    for (int i = 0; i < 2; ++i) {
        int c = wid * 2 + i;
        offA[i] = (size_t)(m0 + c * 16 + srow) * K + skc;
        offB[i] = (size_t)(n0 + c * 16 + srow) * K + skc;
    }

    f32x4 acc[4][4];
#pragma unroll
    for (int i = 0; i < 4; ++i)
#pragma unroll
        for (int j = 0; j < 4; ++j) acc[i][j] = (f32x4){0.f, 0.f, 0.f, 0.f};

    const int wr = wid >> 1, wc = wid & 1;
    const int fm = lane & 15;
    const int fk = (lane >> 4) << 3;

    for (int p = 6 - NP; p < 6; ++p) {
        const bf16* Ab = A  + (size_t)PA[p] * aPS;
        const bf16* Bb = Bt + (size_t)PB[p] * bPS;
        for (int k0 = 0; k0 < K; k0 += 32) {
#pragma unroll
            for (int i = 0; i < 2; ++i) {
                int c = wid * 2 + i;
                __builtin_amdgcn_global_load_lds((const AS1 void*)(Ab + offA[i] + k0),
                                                 (AS3 void*)(As + c * 512), 16, 0, 0);
                __builtin_amdgcn_global_load_lds((const AS1 void*)(Bb + offB[i] + k0),
                                                 (AS3 void*)(Bs + c * 512), 16, 0, 0);
            }
            __syncthreads();
            short8 af[4], bfr[4];
#pragma unroll
            for (int i = 0; i < 4; ++i) {
                af[i]  = *(const short8*)(As + (size_t)(wr * 64 + i * 16 + fm) * 32 + fk);
                bfr[i] = *(const short8*)(Bs + (size_t)(wc * 64 + i * 16 + fm) * 32 + fk);
            }
#pragma unroll
            for (int i = 0; i < 4; ++i)
#pragma unroll
                for (int j = 0; j < 4; ++j)
                    acc[i][j] = __builtin_amdgcn_mfma_f32_16x16x32_bf16(
                        af[i], bfr[j], acc[i][j], 0, 0, 0);
            __syncthreads();
        }
    }

    // epilogue: C/D layout col = lane&15, row = (lane>>4)*4 + r
#pragma unroll
    for (int i = 0; i < 4; ++i) {
        int mbase = m0 + wr * 64 + i * 16 + ((lane >> 4) << 2);
#pragma unroll
        for (int j = 0; j < 4; ++j) {
            int n = n0 + wc * 64 + j * 16 + (lane & 15);
            float bv = bias[n];
#pragma unroll
            for (int r = 0; r < 4; ++r) {
                int m = mbase + r;
                float v = acc[i][j][r] + bv;
                if (LRELU) v = (v >= 0.f) ? v : NEG_SLOPE * v;
                size_t o = (size_t)m * N + n;
                if (resid) v += resid[o];
                C[o] = v;
            }
        }
    }
}

// ---------------------------------------------------------------------------
// scores[bh,t,s] = 8 * sum_e q[t,e]*k[s,e]   (f32, fused qkv stride QLD)
__global__ __launch_bounds__(256)
void attn_scores_kernel(const float* __restrict__ q, const float* __restrict__ k,
                        float* __restrict__ sc) {
    int bh = blockIdx.z;
    int b = bh >> 4, h = bh & 15;
    int t0 = blockIdx.y << 6, s0 = blockIdx.x << 6;
    __shared__ float Qs[64][68];
    __shared__ float Ks[64][68];
    int tid = threadIdx.x;
    int tx = tid & 15, ty = tid >> 4;
    int lr = tid >> 4, le = (tid & 15) << 2;
#pragma unroll
    for (int r = 0; r < 4; ++r) {
        int row = lr + (r << 4);
        float4 qv = *reinterpret_cast<const float4*>(
            q + (size_t)(b * T_SEQ + t0 + row) * QLD + h * HSZ + le);
        *reinterpret_cast<float4*>(&Qs[row][le]) = qv;
        float4 kv = *reinterpret_cast<const float4*>(
            k + (size_t)(b * T_SEQ + s0 + row) * QLD + h * HSZ + le);
        *reinterpret_cast<float4*>(&Ks[row][le]) = kv;
    }
    __syncthreads();
    float acc[4][4] = {};
#pragma unroll 4
    for (int e = 0; e < 64; ++e) {
        float a[4], bb[4];
#pragma unroll
        for (int i = 0; i < 4; ++i) a[i] = Qs[(ty << 2) + i][e];
#pragma unroll
        for (int j = 0; j < 4; ++j) bb[j] = Ks[(tx << 2) + j][e];
#pragma unroll
        for (int i = 0; i < 4; ++i)
#pragma unroll
            for (int j = 0; j < 4; ++j) acc[i][j] += a[i] * bb[j];
    }
#pragma unroll
    for (int i = 0; i < 4; ++i) {
        size_t rbase = ((size_t)bh * T_SEQ + t0 + (ty << 2) + i) * T_SEQ;
#pragma unroll
        for (int j = 0; j < 4; ++j)
            sc[rbase + s0 + (tx << 2) + j] = 8.0f * acc[i][j];
    }
}

// row softmax (optionally causal). One wave per row.
__global__ void softmax_kernel(float* __restrict__ sc, int causal) {
    size_t row = blockIdx.x;
    int t = (int)(row & (T_SEQ - 1));
    float* p = sc + row * T_SEQ;
    int lane = threadIdx.x;
    float vbuf[8];
    float mx = -INFINITY;
#pragma unroll
    for (int j = 0; j < 8; ++j) {
        int s = lane + (j << 6);
        float val = p[s];
        if (causal && s > t) val = -INFINITY;
        vbuf[j] = val;
        mx = fmaxf(mx, val);
    }
#pragma unroll
    for (int off = 32; off > 0; off >>= 1) mx = fmaxf(mx, __shfl_xor(mx, off));
    float sum = 0.f;
#pragma unroll
    for (int j = 0; j < 8; ++j) {
        float e = expf(vbuf[j] - mx);
        vbuf[j] = e;
        sum += e;
    }
#pragma unroll
    for (int off = 32; off > 0; off >>= 1) sum += __shfl_xor(sum, off);
    float inv = 1.f / sum;
#pragma unroll
    for (int j = 0; j < 8; ++j) p[lane + (j << 6)] = vbuf[j] * inv;
}

// out[b,t,h*64+e] = sum_s att[bh,t,s]*v[b,s,h,e]  (v stride QLD, out f32 D-stride)
__global__ __launch_bounds__(256)
void attn_av_kernel(const float* __restrict__ att, const float* __restrict__ v,
                    float* __restrict__ out) {
    int bh = blockIdx.y;
    int b = bh >> 4, h = bh & 15;
    int t0 = blockIdx.x << 6;
    __shared__ float As_[64][20];
    __shared__ float Vs[16][64];
    int tid = threadIdx.x;
    int tx = tid & 15, ty = tid >> 4;
    int at_row = tid >> 2, at_col = (tid & 3) << 2;
    int v_row = tid >> 4, v_col = (tid & 15) << 2;
    float acc[4][4] = {};
    for (int s0 = 0; s0 < T_SEQ; s0 += 16) {
        float4 a4 = *reinterpret_cast<const float4*>(
            att + ((size_t)bh * T_SEQ + t0 + at_row) * T_SEQ + s0 + at_col);
        *reinterpret_cast<float4*>(&As_[at_row][at_col]) = a4;
        float4 v4 = *reinterpret_cast<const float4*>(
            v + (size_t)(b * T_SEQ + s0 + v_row) * QLD + h * HSZ + v_col);
        *reinterpret_cast<float4*>(&Vs[v_row][v_col]) = v4;
        __syncthreads();
#pragma unroll
        for (int kk = 0; kk < 16; ++kk) {
            float a[4], bb[4];
#pragma unroll
            for (int i = 0; i < 4; ++i) a[i] = As_[(ty << 2) + i][kk];
#pragma unroll
            for (int j = 0; j < 4; ++j) bb[j] = Vs[kk][(tx << 2) + j];
#pragma unroll
            for (int i = 0; i < 4; ++i)
#pragma unroll
                for (int j = 0; j < 4; ++j) acc[i][j] += a[i] * bb[j];
        }
        __syncthreads();
    }
#pragma unroll
    for (int i = 0; i < 4; ++i) {
        size_t obase = (size_t)(b * T_SEQ + t0 + (ty << 2) + i) * DMODEL + h * HSZ;
#pragma unroll
        for (int j = 0; j < 4; ++j) out[obase + (tx << 2) + j] = acc[i][j];
    }
}

// ---------------------------------------------------------------------------
extern "C" void kernel_launch(void* const* d_in, const int* in_sizes, int n_in,
                              void* d_out, int out_size, void* d_ws, size_t ws_size,
                              hipStream_t stream) {
    const int*   idx = (const int*)  d_in[0];
    const float* tok = (const float*)d_in[1];
    const float* pos = (const float*)d_in[2];
    const float* Wq  = (const float*)d_in[3];
    const float* bq  = (const float*)d_in[4];
    const float* Wk  = (const float*)d_in[5];
    const float* bk  = (const float*)d_in[6];
    const float* Wv  = (const float*)d_in[7];
    const float* bv  = (const float*)d_in[8];
    const float* Wo  = (const float*)d_in[9];
    const float* bo  = (const float*)d_in[10];
    const float* W1  = (const float*)d_in[11];
    const float* b1  = (const float*)d_in[12];
    const float* W2  = (const float*)d_in[13];
    const float* b2  = (const float*)d_in[14];
    const float* nw  = (const float*)d_in[15];
    const float* fnw = (const float*)d_in[16];
    const float* Wf  = (const float*)d_in[17];
    const float* bf  = (const float*)d_in[18];
    float* out = (float*)d_out;

    const size_t SZ  = (size_t)BT * DMODEL;        // 4M
    const size_t HSZF = (size_t)BT * DFF;          // 16M

    char* w = (char*)d_ws;
    auto alloc = [&](size_t bytes) {
        char* p = w;
        w += (bytes + 255) & ~(size_t)255;
        return p;
    };
    float* x    = (float*)alloc(SZ * 4);
    float* xo   = (float*)alloc(SZ * 4);
    bf16*  xnp  = (bf16*) alloc(SZ * 2 * 3);           // 3 planes
    float* qkv  = (float*)alloc((size_t)BT * QLD * 4);
    float* ao   = (float*)alloc(SZ * 4);
    bf16*  aop  = (bf16*) alloc(SZ * 2 * 3);
    // region: scores (134MB) UNION (hb f32 67MB + hb planes 101MB)
    char*  reg1 = alloc((size_t)BATCH * NHEAD * T_SEQ * T_SEQ * 4 + 34ull * 1024 * 1024);
    float* sc   = (float*)reg1;
    float* hb   = (float*)reg1;
    bf16*  hbp  = (bf16*)(reg1 + HSZF * 4);
    // per-layer weight planes (reused each layer); wf planes union on top
    char*  wreg = alloc(132ull * 1024 * 1024);
    bf16*  qkvTp = (bf16*)wreg;                               // 3 x 3072x1024
    bf16*  woTp  = qkvTp + 3ull * QLD * DMODEL;               // 3 x 1024x1024
    bf16*  w1Tp  = woTp  + 3ull * DMODEL * DMODEL;            // 3 x 4096x1024
    bf16*  w2Tp  = w1Tp  + 3ull * DFF * DMODEL;               // 3 x 1024x4096
    bf16*  wfp   = (bf16*)wreg;                               // 2 x 32000x1024
    float* catb  = (float*)alloc((size_t)NLAYER * QLD * 4);

    cat_bias<<<(NLAYER * QLD) / 256, 256, 0, stream>>>(bq, bk, bv, catb);
    embed_kernel<<<BT, 256, 0, stream>>>(idx, tok, pos, x);

    for (int l = 0; l < NLAYER; ++l) {
        const float* nwl = nw + (size_t)l * DMODEL;
        const float* catbl = catb + (size_t)l * QLD;
        const float* bol = bo + (size_t)l * DMODEL;
        const float* b1l = b1 + (size_t)l * DFF;
        const float* b2l = b2 + (size_t)l * DMODEL;

        // ---- split this layer's weights into transposed bf16 planes ----
        {
            long izs = (long)DMODEL * HSZ;          // per-head input stride
            long ozi = (long)HSZ * DMODEL;          // per-head output stride
            size_t ps = (size_t)QLD * DMODEL;
            dim3 g(HSZ / 32, DMODEL / 32, NHEAD);
            const float* Wql = Wq + (size_t)l * NHEAD * DMODEL * HSZ;
            const float* Wkl = Wk + (size_t)l * NHEAD * DMODEL * HSZ;
            const float* Wvl = Wv + (size_t)l * NHEAD * DMODEL * HSZ;
            transpose_split<<<g, 256, 0, stream>>>(Wql, qkvTp,                 ps, 3, DMODEL, HSZ, izs, ozi);
            transpose_split<<<g, 256, 0, stream>>>(Wkl, qkvTp + 1024ul * 1024, ps, 3, DMODEL, HSZ, izs, ozi);
            transpose_split<<<g, 256, 0, stream>>>(Wvl, qkvTp + 2048ul * 1024, ps, 3, DMODEL, HSZ, izs, ozi);
            transpose_split<<<dim3(DMODEL / 32, DMODEL / 32, 1), 256, 0, stream>>>(
                Wo + (size_t)l * DMODEL * DMODEL, woTp, (size_t)DMODEL * DMODEL, 3, DMODEL, DMODEL, 0, 0);
            transpose_split<<<dim3(DFF / 32, DMODEL / 32, 1), 256, 0, stream>>>(
                W1 + (size_t)l * DMODEL * DFF, w1Tp, (size_t)DFF * DMODEL, 3, DMODEL, DFF, 0, 0);
            transpose_split<<<dim3(DMODEL / 32, DFF / 32, 1), 256, 0, stream>>>(
                W2 + (size_t)l * DMODEL * DFF, w2Tp, (size_t)DMODEL * DFF, 3, DFF, DMODEL, 0, 0);
        }

        auto attn = [&](const float* resid, float* outp, int causal) {
            // xnp already holds rms-normed input planes
            gemm_split<6, false><<<dim3(QLD / 128, BT / 128), 256, 0, stream>>>(
                xnp, SZ, qkvTp, (size_t)QLD * DMODEL, catbl, nullptr, qkv, BT, QLD, DMODEL);
            attn_scores_kernel<<<dim3(T_SEQ / 64, T_SEQ / 64, BATCH * NHEAD), 256, 0, stream>>>(
                qkv, qkv + 1024, sc);
            softmax_kernel<<<BATCH * NHEAD * T_SEQ, 64, 0, stream>>>(sc, causal);
            attn_av_kernel<<<dim3(T_SEQ / 64, BATCH * NHEAD), 256, 0, stream>>>(
                sc, qkv + 2048, ao);
            split3_kernel<<<2048, 256, 0, stream>>>(ao, aop, SZ, SZ / 4);
            gemm_split<6, false><<<dim3(DMODEL / 128, BT / 128), 256, 0, stream>>>(
                aop, SZ, woTp, (size_t)DMODEL * DMODEL, bol, resid, outp, BT, DMODEL, DMODEL);
        };

        // x_out1 = x + attn(rms(x), unmasked)
        rms_split<<<BT, 256, 0, stream>>>(x, nwl, xnp, SZ);
        attn(x, xo, 0);
        // x_out2 = x + ffn(rms(x_out1))      (residual from ORIGINAL x)
        rms_split<<<BT, 256, 0, stream>>>(xo, nwl, xnp, SZ);
        gemm_split<6, true><<<dim3(DFF / 128, BT / 128), 256, 0, stream>>>(
            xnp, SZ, w1Tp, (size_t)DFF * DMODEL, b1l, nullptr, hb, BT, DFF, DMODEL);
        split3_kernel<<<2048, 256, 0, stream>>>(hb, hbp, HSZF, HSZF / 4);
        gemm_split<6, false><<<dim3(DMODEL / 128, BT / 128), 256, 0, stream>>>(
            hbp, HSZF, w2Tp, (size_t)DMODEL * DFF, b2l, x, xo, BT, DMODEL, DFF);
        // x = x_out2 + attn(rms(x_out2), masked)
        rms_split<<<BT, 256, 0, stream>>>(xo, nwl, xnp, SZ);
        attn(xo, x, 1);
    }

    // final: logits = rms(x, fnw) @ Wf + bf   (3-pair split: error ~2^-18)
    rms_split<<<BT, 256, 0, stream>>>(x, fnw, xnp, SZ);
    transpose_split<<<dim3(VOCAB / 32, DMODEL / 32, 1), 256, 0, stream>>>(
        Wf, wfp, (size_t)VOCAB * DMODEL, 2, DMODEL, VOCAB, 0, 0);
    gemm_split<3, false><<<dim3(VOCAB / 128, BT / 128), 256, 0, stream>>>(
        xnp, SZ, wfp, (size_t)VOCAB * DMODEL, bf, nullptr, out, BT, VOCAB, DMODEL);
}

// Round 4
// 14193.027 us; speedup vs baseline: 1.7740x; 1.2497x over previous
//
#include <hip/hip_runtime.h>
#include <hip/hip_bf16.h>
#include <cstdint>
#include <cstddef>

#define T_SEQ   512
#define BATCH   8
#define BT      4096
#define DMODEL  1024
#define NHEAD   16
#define HSZ     64
#define NLAYER  8
#define DFF     4096
#define VOCAB   32000
#define EPS     1e-6f
#define NEG_SLOPE 0.1f
#define QLD     3072    // fused qkv row stride

typedef __attribute__((ext_vector_type(8))) short short8;
typedef __attribute__((ext_vector_type(4))) float f32x4;
typedef __hip_bfloat16 bf16;

#define AS1 __attribute__((address_space(1)))
#define AS3 __attribute__((address_space(3)))

// ---------------------------------------------------------------------------
__global__ void embed_kernel(const int* __restrict__ idx,
                             const float* __restrict__ tok,
                             const float* __restrict__ pos,
                             float* __restrict__ x) {
    int bt  = blockIdx.x;
    int tid = threadIdx.x;
    int token = idx[bt];
    int t = bt & (T_SEQ - 1);
    float4 a = reinterpret_cast<const float4*>(tok + (size_t)token * DMODEL)[tid];
    float4 p = reinterpret_cast<const float4*>(pos + (size_t)t * DMODEL)[tid];
    reinterpret_cast<float4*>(x + (size_t)bt * DMODEL)[tid] =
        make_float4(a.x + p.x, a.y + p.y, a.z + p.z, a.w + p.w);
}

// ---------------------------------------------------------------------------
// exact 3-way bf16 split of an f32 value (x == h + m + l exactly)
__device__ __forceinline__ void split3v(float v, bf16& h, bf16& m, bf16& l) {
    h = __float2bfloat16(v);
    float r1 = v - __bfloat162float(h);
    m = __float2bfloat16(r1);
    float r2 = r1 - __bfloat162float(m);
    l = __float2bfloat16(r2);
}

// ---------------------------------------------------------------------------
// rmsnorm f32 -> 3 bf16 planes
__global__ void rms_split(const float* __restrict__ x,
                          const float* __restrict__ w,
                          bf16* __restrict__ out, size_t planeStride) {
    int row = blockIdx.x;
    int tid = threadIdx.x;
    float4 v = reinterpret_cast<const float4*>(x + (size_t)row * DMODEL)[tid];
    float ss = v.x * v.x + v.y * v.y + v.z * v.z + v.w * v.w;
#pragma unroll
    for (int off = 32; off > 0; off >>= 1) ss += __shfl_xor(ss, off);
    __shared__ float wsum[4];
    if ((tid & 63) == 0) wsum[tid >> 6] = ss;
    __syncthreads();
    float tot = wsum[0] + wsum[1] + wsum[2] + wsum[3];
    float scale = rsqrtf(tot * (1.0f / DMODEL) + EPS);
    float4 wv = reinterpret_cast<const float4*>(w)[tid];
    float o[4] = {v.x * scale * wv.x, v.y * scale * wv.y,
                  v.z * scale * wv.z, v.w * scale * wv.w};
    size_t base = (size_t)row * DMODEL + tid * 4;
#pragma unroll
    for (int j = 0; j < 4; ++j) {
        bf16 h, m, l;
        split3v(o[j], h, m, l);
        out[base + j] = h;
        out[planeStride + base + j] = m;
        out[2 * planeStride + base + j] = l;
    }
}

// ---------------------------------------------------------------------------
// Tiled transpose + split: in (R,C) f32 -> out (C,R) bf16 x nPlanes
__global__ __launch_bounds__(256)
void transpose_split(const float* __restrict__ in, bf16* __restrict__ out,
                     size_t planeStride, int nPlanes, int R, int C,
                     long izs, long ozi) {
    int z = blockIdx.z;
    in  += (size_t)z * izs;
    out += (size_t)z * ozi;
    __shared__ float tile[32][33];
    int r0 = blockIdx.y << 5, c0 = blockIdx.x << 5;
    int tx = threadIdx.x & 31, ty = threadIdx.x >> 5;
#pragma unroll
    for (int i = 0; i < 4; ++i) {
        int r = ty + (i << 3);
        tile[r][tx] = in[(size_t)(r0 + r) * C + c0 + tx];
    }
    __syncthreads();
#pragma unroll
    for (int i = 0; i < 4; ++i) {
        int c = ty + (i << 3);
        float v = tile[tx][c];
        size_t o = (size_t)(c0 + c) * R + r0 + tx;
        bf16 h = __float2bfloat16(v);
        out[o] = h;
        if (nPlanes > 1) {
            float r1 = v - __bfloat162float(h);
            bf16 m = __float2bfloat16(r1);
            out[planeStride + o] = m;
            if (nPlanes > 2) {
                float r2 = r1 - __bfloat162float(m);
                out[2 * planeStride + o] = __float2bfloat16(r2);
            }
        }
    }
}

// concat per-layer qkv bias into (L, 3072) f32
__global__ void cat_bias(const float* __restrict__ bq, const float* __restrict__ bk,
                         const float* __restrict__ bv, float* __restrict__ cb) {
    int i = blockIdx.x * 256 + threadIdx.x;
    int l = i / QLD, r = i - l * QLD;
    const float* src = (r < 1024) ? bq : ((r < 2048) ? bk : bv);
    cb[i] = src[l * 1024 + (r & 1023)];
}

// ---------------------------------------------------------------------------
// Merged-pass split-precision MFMA GEMM.
// C = sum_p A[PA[p]] @ B[PB[p]]^T (+bias, lrelu, resid) — all passes fused in
// one K-loop: per K-step stage ALL planes (48KB/32KB LDS), one barrier pair,
// NP*16 MFMA. LDS 16B-slot XOR swizzle (slot ^= (row>>1)&3), pre-swizzled on
// the global source side (gload_lds dest must stay linear).
// Grid: 1D, m-fastest + bijective XCD swizzle (requires gridDim.x % 8 == 0).
template <int NP, bool LRELU, bool SPLITOUT>
__global__ __launch_bounds__(256, 2)
void gemm_ms(const bf16* __restrict__ A, size_t aPS,
             const bf16* __restrict__ Bt, size_t bPS,
             const float* __restrict__ bias,
             const float* __restrict__ resid,
             float* __restrict__ C, bf16* __restrict__ Cp, size_t cPS,
             int Mb, int N, int K) {
    constexpr int NPA = (NP == 6) ? 3 : 2;
    constexpr int NPB = (NP == 6) ? 3 : 2;
    constexpr int PA[6] = {1, 0, 2, 0, 1, 0};   // mm,hl,lh,hm,mh,hh
    constexpr int PB[6] = {1, 2, 0, 1, 0, 0};
    __shared__ bf16 As[NPA * 4096];     // per plane: 128 rows x 32 k (64B rows)
    __shared__ bf16 Bs[NPB * 4096];

    // XCD-aware bijective swizzle (gridDim.x % 8 == 0), then m-fastest.
    int chunk = gridDim.x >> 3;
    int bid = blockIdx.x;
    int sw = (bid & 7) * chunk + (bid >> 3);
    int m0 = (sw % Mb) << 7;
    int n0 = (sw / Mb) << 7;

    const int tid  = threadIdx.x;
    const int lane = tid & 63;
    const int wid  = tid >> 6;

    // staging: chunk c = rows [c*16,c*16+16). lane -> row c*16+(lane>>2);
    // global k-slot pre-swizzled: (lane&3) ^ ((lane>>3)&3)  [= slot ^ (row>>1)&3]
    const int srow = lane >> 2;
    const int ssk  = (((lane & 3) ^ ((lane >> 3) & 3)) << 3);
    size_t offA[2], offB[2];
#pragma unroll
    for (int i = 0; i < 2; ++i) {
        int c = wid * 2 + i;
        offA[i] = (size_t)(m0 + c * 16 + srow) * K + ssk;
        offB[i] = (size_t)(n0 + c * 16 + srow) * K + ssk;
    }

    f32x4 acc[4][4];
#pragma unroll
    for (int i = 0; i < 4; ++i)
#pragma unroll
        for (int j = 0; j < 4; ++j) acc[i][j] = (f32x4){0.f, 0.f, 0.f, 0.f};

    const int wr = wid >> 1, wc = wid & 1;
    const int fm = lane & 15;
    // read slot' = (lane>>4) ^ ((row>>1)&3); (row>>1)&3 == ((lane&15)>>1)&3
    const int rslot = (((lane >> 4) ^ ((lane >> 1) & 3)) & 3) << 3;
    int foffA[4], foffB[4];
#pragma unroll
    for (int i = 0; i < 4; ++i) {
        foffA[i] = (wr * 64 + i * 16 + fm) * 32 + rslot;
        foffB[i] = (wc * 64 + i * 16 + fm) * 32 + rslot;
    }

    for (int k0 = 0; k0 < K; k0 += 32) {
#pragma unroll
        for (int p = 0; p < NPA; ++p)
#pragma unroll
            for (int i = 0; i < 2; ++i) {
                int c = wid * 2 + i;
                __builtin_amdgcn_global_load_lds(
                    (const AS1 void*)(A + p * aPS + offA[i] + k0),
                    (AS3 void*)(As + p * 4096 + c * 512), 16, 0, 0);
            }
#pragma unroll
        for (int p = 0; p < NPB; ++p)
#pragma unroll
            for (int i = 0; i < 2; ++i) {
                int c = wid * 2 + i;
                __builtin_amdgcn_global_load_lds(
                    (const AS1 void*)(Bt + p * bPS + offB[i] + k0),
                    (AS3 void*)(Bs + p * 4096 + c * 512), 16, 0, 0);
            }
        __syncthreads();

        short8 af[NPA][4], bfr[NPB][4];
#pragma unroll
        for (int p = 0; p < NPA; ++p)
#pragma unroll
            for (int i = 0; i < 4; ++i)
                af[p][i] = *(const short8*)(As + p * 4096 + foffA[i]);
#pragma unroll
        for (int p = 0; p < NPB; ++p)
#pragma unroll
            for (int j = 0; j < 4; ++j)
                bfr[p][j] = *(const short8*)(Bs + p * 4096 + foffB[j]);

#pragma unroll
        for (int p = 6 - NP; p < 6; ++p)
#pragma unroll
            for (int i = 0; i < 4; ++i)
#pragma unroll
                for (int j = 0; j < 4; ++j)
                    acc[i][j] = __builtin_amdgcn_mfma_f32_16x16x32_bf16(
                        af[PA[p]][i], bfr[PB[p]][j], acc[i][j], 0, 0, 0);
        __syncthreads();
    }

    // epilogue: C/D layout col = lane&15, row = (lane>>4)*4 + r
#pragma unroll
    for (int i = 0; i < 4; ++i) {
        int mbase = m0 + wr * 64 + i * 16 + ((lane >> 4) << 2);
#pragma unroll
        for (int j = 0; j < 4; ++j) {
            int n = n0 + wc * 64 + j * 16 + (lane & 15);
            float bv = bias[n];
#pragma unroll
            for (int r = 0; r < 4; ++r) {
                int m = mbase + r;
                float v = acc[i][j][r] + bv;
                if (LRELU) v = (v >= 0.f) ? v : NEG_SLOPE * v;
                size_t o = (size_t)m * N + n;
                if (SPLITOUT) {
                    bf16 h, mm, ll;
                    split3v(v, h, mm, ll);
                    Cp[o] = h;
                    Cp[cPS + o] = mm;
                    Cp[2 * cPS + o] = ll;
                } else {
                    if (resid) v += resid[o];
                    C[o] = v;
                }
            }
        }
    }
}

// ---------------------------------------------------------------------------
// scores[bh,t,s] = 8 * sum_e q[t,e]*k[s,e]   (f32, fused qkv stride QLD)
__global__ __launch_bounds__(256)
void attn_scores_kernel(const float* __restrict__ q, const float* __restrict__ k,
                        float* __restrict__ sc) {
    int bh = blockIdx.z;
    int b = bh >> 4, h = bh & 15;
    int t0 = blockIdx.y << 6, s0 = blockIdx.x << 6;
    __shared__ float Qs[64][68];
    __shared__ float Ks[64][68];
    int tid = threadIdx.x;
    int tx = tid & 15, ty = tid >> 4;
    int lr = tid >> 4, le = (tid & 15) << 2;
#pragma unroll
    for (int r = 0; r < 4; ++r) {
        int row = lr + (r << 4);
        float4 qv = *reinterpret_cast<const float4*>(
            q + (size_t)(b * T_SEQ + t0 + row) * QLD + h * HSZ + le);
        *reinterpret_cast<float4*>(&Qs[row][le]) = qv;
        float4 kv = *reinterpret_cast<const float4*>(
            k + (size_t)(b * T_SEQ + s0 + row) * QLD + h * HSZ + le);
        *reinterpret_cast<float4*>(&Ks[row][le]) = kv;
    }
    __syncthreads();
    float acc[4][4] = {};
#pragma unroll 4
    for (int e = 0; e < 64; ++e) {
        float a[4], bb[4];
#pragma unroll
        for (int i = 0; i < 4; ++i) a[i] = Qs[(ty << 2) + i][e];
#pragma unroll
        for (int j = 0; j < 4; ++j) bb[j] = Ks[(tx << 2) + j][e];
#pragma unroll
        for (int i = 0; i < 4; ++i)
#pragma unroll
            for (int j = 0; j < 4; ++j) acc[i][j] += a[i] * bb[j];
    }
#pragma unroll
    for (int i = 0; i < 4; ++i) {
        size_t rbase = ((size_t)bh * T_SEQ + t0 + (ty << 2) + i) * T_SEQ;
#pragma unroll
        for (int j = 0; j < 4; ++j)
            sc[rbase + s0 + (tx << 2) + j] = 8.0f * acc[i][j];
    }
}

// row softmax (optionally causal). One wave per row.
__global__ void softmax_kernel(float* __restrict__ sc, int causal) {
    size_t row = blockIdx.x;
    int t = (int)(row & (T_SEQ - 1));
    float* p = sc + row * T_SEQ;
    int lane = threadIdx.x;
    float vbuf[8];
    float mx = -INFINITY;
#pragma unroll
    for (int j = 0; j < 8; ++j) {
        int s = lane + (j << 6);
        float val = p[s];
        if (causal && s > t) val = -INFINITY;
        vbuf[j] = val;
        mx = fmaxf(mx, val);
    }
#pragma unroll
    for (int off = 32; off > 0; off >>= 1) mx = fmaxf(mx, __shfl_xor(mx, off));
    float sum = 0.f;
#pragma unroll
    for (int j = 0; j < 8; ++j) {
        float e = expf(vbuf[j] - mx);
        vbuf[j] = e;
        sum += e;
    }
#pragma unroll
    for (int off = 32; off > 0; off >>= 1) sum += __shfl_xor(sum, off);
    float inv = 1.f / sum;
#pragma unroll
    for (int j = 0; j < 8; ++j) p[lane + (j << 6)] = vbuf[j] * inv;
}

// out planes[b,t,h*64+e] = split3(sum_s att[bh,t,s]*v[b,s,h,e])
__global__ __launch_bounds__(256)
void attn_av_split(const float* __restrict__ att, const float* __restrict__ v,
                   bf16* __restrict__ out, size_t planeStride) {
    int bh = blockIdx.y;
    int b = bh >> 4, h = bh & 15;
    int t0 = blockIdx.x << 6;
    __shared__ float As_[64][20];
    __shared__ float Vs[16][64];
    int tid = threadIdx.x;
    int tx = tid & 15, ty = tid >> 4;
    int at_row = tid >> 2, at_col = (tid & 3) << 2;
    int v_row = tid >> 4, v_col = (tid & 15) << 2;
    float acc[4][4] = {};
    for (int s0 = 0; s0 < T_SEQ; s0 += 16) {
        float4 a4 = *reinterpret_cast<const float4*>(
            att + ((size_t)bh * T_SEQ + t0 + at_row) * T_SEQ + s0 + at_col);
        *reinterpret_cast<float4*>(&As_[at_row][at_col]) = a4;
        float4 v4 = *reinterpret_cast<const float4*>(
            v + (size_t)(b * T_SEQ + s0 + v_row) * QLD + h * HSZ + v_col);
        *reinterpret_cast<float4*>(&Vs[v_row][v_col]) = v4;
        __syncthreads();
#pragma unroll
        for (int kk = 0; kk < 16; ++kk) {
            float a[4], bb[4];
#pragma unroll
            for (int i = 0; i < 4; ++i) a[i] = As_[(ty << 2) + i][kk];
#pragma unroll
            for (int j = 0; j < 4; ++j) bb[j] = Vs[kk][(tx << 2) + j];
#pragma unroll
            for (int i = 0; i < 4; ++i)
#pragma unroll
                for (int j = 0; j < 4; ++j) acc[i][j] += a[i] * bb[j];
        }
        __syncthreads();
    }
#pragma unroll
    for (int i = 0; i < 4; ++i) {
        size_t obase = (size_t)(b * T_SEQ + t0 + (ty << 2) + i) * DMODEL + h * HSZ;
#pragma unroll
        for (int j = 0; j < 4; ++j) {
            bf16 h_, m_, l_;
            split3v(acc[i][j], h_, m_, l_);
            size_t o = obase + (tx << 2) + j;
            out[o] = h_;
            out[planeStride + o] = m_;
            out[2 * planeStride + o] = l_;
        }
    }
}

// ---------------------------------------------------------------------------
extern "C" void kernel_launch(void* const* d_in, const int* in_sizes, int n_in,
                              void* d_out, int out_size, void* d_ws, size_t ws_size,
                              hipStream_t stream) {
    const int*   idx = (const int*)  d_in[0];
    const float* tok = (const float*)d_in[1];
    const float* pos = (const float*)d_in[2];
    const float* Wq  = (const float*)d_in[3];
    const float* bq  = (const float*)d_in[4];
    const float* Wk  = (const float*)d_in[5];
    const float* bk  = (const float*)d_in[6];
    const float* Wv  = (const float*)d_in[7];
    const float* bv  = (const float*)d_in[8];
    const float* Wo  = (const float*)d_in[9];
    const float* bo  = (const float*)d_in[10];
    const float* W1  = (const float*)d_in[11];
    const float* b1  = (const float*)d_in[12];
    const float* W2  = (const float*)d_in[13];
    const float* b2  = (const float*)d_in[14];
    const float* nw  = (const float*)d_in[15];
    const float* fnw = (const float*)d_in[16];
    const float* Wf  = (const float*)d_in[17];
    const float* bf  = (const float*)d_in[18];
    float* out = (float*)d_out;

    const size_t SZ   = (size_t)BT * DMODEL;    // 4M
    const size_t HSZF = (size_t)BT * DFF;       // 16M

    char* w = (char*)d_ws;
    auto alloc = [&](size_t bytes) {
        char* p = w;
        w += (bytes + 255) & ~(size_t)255;
        return p;
    };
    float* x    = (float*)alloc(SZ * 4);
    float* xo   = (float*)alloc(SZ * 4);
    bf16*  xnp  = (bf16*) alloc(SZ * 2 * 3);
    float* qkv  = (float*)alloc((size_t)BT * QLD * 4);
    bf16*  aop  = (bf16*) alloc(SZ * 2 * 3);
    // scores (134MB) UNION ffn-hidden planes (100MB)
    char*  reg1 = alloc((size_t)BATCH * NHEAD * T_SEQ * T_SEQ * 4);
    float* sc   = (float*)reg1;
    bf16*  hbp  = (bf16*)reg1;
    // per-layer weight planes (reused); wf planes union on top
    char*  wreg = alloc(132ull * 1024 * 1024);
    bf16*  qkvTp = (bf16*)wreg;                               // 3 x 3072x1024
    bf16*  woTp  = qkvTp + 3ull * QLD * DMODEL;               // 3 x 1024x1024
    bf16*  w1Tp  = woTp  + 3ull * DMODEL * DMODEL;            // 3 x 4096x1024
    bf16*  w2Tp  = w1Tp  + 3ull * DFF * DMODEL;               // 3 x 1024x4096
    bf16*  wfp   = (bf16*)wreg;                               // 2 x 32000x1024
    float* catb  = (float*)alloc((size_t)NLAYER * QLD * 4);

    cat_bias<<<(NLAYER * QLD) / 256, 256, 0, stream>>>(bq, bk, bv, catb);
    embed_kernel<<<BT, 256, 0, stream>>>(idx, tok, pos, x);

    for (int l = 0; l < NLAYER; ++l) {
        const float* nwl = nw + (size_t)l * DMODEL;
        const float* catbl = catb + (size_t)l * QLD;
        const float* bol = bo + (size_t)l * DMODEL;
        const float* b1l = b1 + (size_t)l * DFF;
        const float* b2l = b2 + (size_t)l * DMODEL;

        // split this layer's weights into transposed bf16 planes
        {
            long izs = (long)DMODEL * HSZ;
            long ozi = (long)HSZ * DMODEL;
            size_t ps = (size_t)QLD * DMODEL;
            dim3 g(HSZ / 32, DMODEL / 32, NHEAD);
            const float* Wql = Wq + (size_t)l * NHEAD * DMODEL * HSZ;
            const float* Wkl = Wk + (size_t)l * NHEAD * DMODEL * HSZ;
            const float* Wvl = Wv + (size_t)l * NHEAD * DMODEL * HSZ;
            transpose_split<<<g, 256, 0, stream>>>(Wql, qkvTp,                 ps, 3, DMODEL, HSZ, izs, ozi);
            transpose_split<<<g, 256, 0, stream>>>(Wkl, qkvTp + 1024ul * 1024, ps, 3, DMODEL, HSZ, izs, ozi);
            transpose_split<<<g, 256, 0, stream>>>(Wvl, qkvTp + 2048ul * 1024, ps, 3, DMODEL, HSZ, izs, ozi);
            transpose_split<<<dim3(DMODEL / 32, DMODEL / 32, 1), 256, 0, stream>>>(
                Wo + (size_t)l * DMODEL * DMODEL, woTp, (size_t)DMODEL * DMODEL, 3, DMODEL, DMODEL, 0, 0);
            transpose_split<<<dim3(DFF / 32, DMODEL / 32, 1), 256, 0, stream>>>(
                W1 + (size_t)l * DMODEL * DFF, w1Tp, (size_t)DFF * DMODEL, 3, DMODEL, DFF, 0, 0);
            transpose_split<<<dim3(DMODEL / 32, DFF / 32, 1), 256, 0, stream>>>(
                W2 + (size_t)l * DMODEL * DFF, w2Tp, (size_t)DMODEL * DFF, 3, DFF, DMODEL, 0, 0);
        }

        auto attn = [&](const float* resid, float* outp, int causal) {
            // xnp holds rms-normed input planes
            gemm_ms<6, false, false><<<dim3((BT / 128) * (QLD / 128)), 256, 0, stream>>>(
                xnp, SZ, qkvTp, (size_t)QLD * DMODEL, catbl, nullptr,
                qkv, nullptr, 0, BT / 128, QLD, DMODEL);
            attn_scores_kernel<<<dim3(T_SEQ / 64, T_SEQ / 64, BATCH * NHEAD), 256, 0, stream>>>(
                qkv, qkv + 1024, sc);
            softmax_kernel<<<BATCH * NHEAD * T_SEQ, 64, 0, stream>>>(sc, causal);
            attn_av_split<<<dim3(T_SEQ / 64, BATCH * NHEAD), 256, 0, stream>>>(
                sc, qkv + 2048, aop, SZ);
            gemm_ms<6, false, false><<<dim3((BT / 128) * (DMODEL / 128)), 256, 0, stream>>>(
                aop, SZ, woTp, (size_t)DMODEL * DMODEL, bol, resid,
                outp, nullptr, 0, BT / 128, DMODEL, DMODEL);
        };

        // x_out1 = x + attn(rms(x), unmasked)
        rms_split<<<BT, 256, 0, stream>>>(x, nwl, xnp, SZ);
        attn(x, xo, 0);
        // x_out2 = x + ffn(rms(x_out1))      (residual from ORIGINAL x)
        rms_split<<<BT, 256, 0, stream>>>(xo, nwl, xnp, SZ);
        gemm_ms<6, true, true><<<dim3((BT / 128) * (DFF / 128)), 256, 0, stream>>>(
            xnp, SZ, w1Tp, (size_t)DFF * DMODEL, b1l, nullptr,
            nullptr, hbp, HSZF, BT / 128, DFF, DMODEL);
        gemm_ms<6, false, false><<<dim3((BT / 128) * (DMODEL / 128)), 256, 0, stream>>>(
            hbp, HSZF, w2Tp, (size_t)DMODEL * DFF, b2l, x,
            xo, nullptr, 0, BT / 128, DMODEL, DFF);
        // x = x_out2 + attn(rms(x_out2), masked)
        rms_split<<<BT, 256, 0, stream>>>(xo, nwl, xnp, SZ);
        attn(xo, x, 1);
    }

    // final: logits = rms(x, fnw) @ Wf + bf   (3-pass split)
    rms_split<<<BT, 256, 0, stream>>>(x, fnw, xnp, SZ);
    transpose_split<<<dim3(VOCAB / 32, DMODEL / 32, 1), 256, 0, stream>>>(
        Wf, wfp, (size_t)VOCAB * DMODEL, 2, DMODEL, VOCAB, 0, 0);
    gemm_ms<3, false, false><<<dim3((BT / 128) * (VOCAB / 128)), 256, 0, stream>>>(
        xnp, SZ, wfp, (size_t)VOCAB * DMODEL, bf, nullptr,
        out, nullptr, 0, BT / 128, VOCAB, DMODEL);
}

// Round 5
// 12927.138 us; speedup vs baseline: 1.9477x; 1.0979x over previous
//
#include <hip/hip_runtime.h>
#include <hip/hip_bf16.h>
#include <cstdint>
#include <cstddef>

#define T_SEQ   512
#define BATCH   8
#define BT      4096
#define DMODEL  1024
#define NHEAD   16
#define HSZ     64
#define NLAYER  8
#define DFF     4096
#define VOCAB   32000
#define EPS     1e-6f
#define NEG_SLOPE 0.1f
#define QLD     3072    // fused qkv row stride

typedef __attribute__((ext_vector_type(8))) short short8;
typedef __attribute__((ext_vector_type(4))) float f32x4;
typedef __hip_bfloat16 bf16;

#define AS1 __attribute__((address_space(1)))
#define AS3 __attribute__((address_space(3)))

// ---------------------------------------------------------------------------
__global__ void embed_kernel(const int* __restrict__ idx,
                             const float* __restrict__ tok,
                             const float* __restrict__ pos,
                             float* __restrict__ x) {
    int bt  = blockIdx.x;
    int tid = threadIdx.x;
    int token = idx[bt];
    int t = bt & (T_SEQ - 1);
    float4 a = reinterpret_cast<const float4*>(tok + (size_t)token * DMODEL)[tid];
    float4 p = reinterpret_cast<const float4*>(pos + (size_t)t * DMODEL)[tid];
    reinterpret_cast<float4*>(x + (size_t)bt * DMODEL)[tid] =
        make_float4(a.x + p.x, a.y + p.y, a.z + p.z, a.w + p.w);
}

// ---------------------------------------------------------------------------
// exact 3-way bf16 split of an f32 value (x == h + m + l exactly)
__device__ __forceinline__ void split3v(float v, bf16& h, bf16& m, bf16& l) {
    h = __float2bfloat16(v);
    float r1 = v - __bfloat162float(h);
    m = __float2bfloat16(r1);
    float r2 = r1 - __bfloat162float(m);
    l = __float2bfloat16(r2);
}

// ---------------------------------------------------------------------------
// rmsnorm f32 -> 3 bf16 planes
__global__ void rms_split(const float* __restrict__ x,
                          const float* __restrict__ w,
                          bf16* __restrict__ out, size_t planeStride) {
    int row = blockIdx.x;
    int tid = threadIdx.x;
    float4 v = reinterpret_cast<const float4*>(x + (size_t)row * DMODEL)[tid];
    float ss = v.x * v.x + v.y * v.y + v.z * v.z + v.w * v.w;
#pragma unroll
    for (int off = 32; off > 0; off >>= 1) ss += __shfl_xor(ss, off);
    __shared__ float wsum[4];
    if ((tid & 63) == 0) wsum[tid >> 6] = ss;
    __syncthreads();
    float tot = wsum[0] + wsum[1] + wsum[2] + wsum[3];
    float scale = rsqrtf(tot * (1.0f / DMODEL) + EPS);
    float4 wv = reinterpret_cast<const float4*>(w)[tid];
    float o[4] = {v.x * scale * wv.x, v.y * scale * wv.y,
                  v.z * scale * wv.z, v.w * scale * wv.w};
    size_t base = (size_t)row * DMODEL + tid * 4;
#pragma unroll
    for (int j = 0; j < 4; ++j) {
        bf16 h, m, l;
        split3v(o[j], h, m, l);
        out[base + j] = h;
        out[planeStride + base + j] = m;
        out[2 * planeStride + base + j] = l;
    }
}

// ---------------------------------------------------------------------------
// Tiled transpose + split: in (R,C) f32 -> out (C,R) bf16 x nPlanes
__global__ __launch_bounds__(256)
void transpose_split(const float* __restrict__ in, bf16* __restrict__ out,
                     size_t planeStride, int nPlanes, int R, int C,
                     long izs, long ozi) {
    int z = blockIdx.z;
    in  += (size_t)z * izs;
    out += (size_t)z * ozi;
    __shared__ float tile[32][33];
    int r0 = blockIdx.y << 5, c0 = blockIdx.x << 5;
    int tx = threadIdx.x & 31, ty = threadIdx.x >> 5;
#pragma unroll
    for (int i = 0; i < 4; ++i) {
        int r = ty + (i << 3);
        tile[r][tx] = in[(size_t)(r0 + r) * C + c0 + tx];
    }
    __syncthreads();
#pragma unroll
    for (int i = 0; i < 4; ++i) {
        int c = ty + (i << 3);
        float v = tile[tx][c];
        size_t o = (size_t)(c0 + c) * R + r0 + tx;
        bf16 h = __float2bfloat16(v);
        out[o] = h;
        if (nPlanes > 1) {
            float r1 = v - __bfloat162float(h);
            bf16 m = __float2bfloat16(r1);
            out[planeStride + o] = m;
            if (nPlanes > 2) {
                float r2 = r1 - __bfloat162float(m);
                out[2 * planeStride + o] = __float2bfloat16(r2);
            }
        }
    }
}

// concat per-layer qkv bias into (L, 3072) f32
__global__ void cat_bias(const float* __restrict__ bq, const float* __restrict__ bk,
                         const float* __restrict__ bv, float* __restrict__ cb) {
    int i = blockIdx.x * 256 + threadIdx.x;
    int l = i / QLD, r = i - l * QLD;
    const float* src = (r < 1024) ? bq : ((r < 2048) ? bk : bv);
    cb[i] = src[l * 1024 + (r & 1023)];
}

// ---------------------------------------------------------------------------
// Merged-pass split-precision MFMA GEMM (M fixed = 4096 = 32 m-blocks).
// C = sum_p A[PA[p]] @ B[PB[p]]^T (+bias, lrelu, resid); all split passes in
// one K-loop (one barrier pair per K-step, NP*16 MFMA). LDS 16B-slot XOR
// swizzle, pre-swizzled on the global source side (gload_lds dest linear).
// Grid 1D = 32*Nb, XCD-swizzled (grid%8==0), then PANEL n-cols per panel with
// m-fastest inside: A re-fetched once per panel, B panel L2/L3-resident.
template <int NP, bool LRELU, bool SPLITOUT>
__global__ __launch_bounds__(256, 2)
void gemm_ms(const bf16* __restrict__ A, size_t aPS,
             const bf16* __restrict__ Bt, size_t bPS,
             const float* __restrict__ bias,
             const float* __restrict__ resid,
             float* __restrict__ C, bf16* __restrict__ Cp, size_t cPS,
             int N, int K) {
    constexpr int NPA = (NP == 6) ? 3 : 2;
    constexpr int NPB = (NP == 6) ? 3 : 2;
    constexpr int PA[6] = {1, 0, 2, 0, 1, 0};   // mm,hl,lh,hm,mh,hh
    constexpr int PB[6] = {1, 2, 0, 1, 0, 0};
    __shared__ bf16 As[NPA * 4096];     // per plane: 128 rows x 32 k (64B rows)
    __shared__ bf16 Bs[NPB * 4096];

    // XCD swizzle -> panel decomposition (PANEL=8 n-blocks, m-fastest inside)
    int chunk = gridDim.x >> 3;
    int bid = blockIdx.x;
    int sw = (bid & 7) * chunk + (bid >> 3);
    int p  = sw >> 8;                   // / (32 m-blocks * 8 panel)
    int r  = sw & 255;
    int m0 = (r & 31) << 7;
    int n0 = ((p << 3) + (r >> 5)) << 7;

    const int tid  = threadIdx.x;
    const int lane = tid & 63;
    const int wid  = tid >> 6;

    // staging: chunk c = rows [c*16,c*16+16). lane -> row c*16+(lane>>2);
    // global k-slot pre-swizzled: (lane&3) ^ ((lane>>3)&3)  [= slot ^ (row>>1)&3]
    const int srow = lane >> 2;
    const int ssk  = (((lane & 3) ^ ((lane >> 3) & 3)) << 3);
    size_t offA[2], offB[2];
#pragma unroll
    for (int i = 0; i < 2; ++i) {
        int c = wid * 2 + i;
        offA[i] = (size_t)(m0 + c * 16 + srow) * K + ssk;
        offB[i] = (size_t)(n0 + c * 16 + srow) * K + ssk;
    }

    f32x4 acc[4][4];
#pragma unroll
    for (int i = 0; i < 4; ++i)
#pragma unroll
        for (int j = 0; j < 4; ++j) acc[i][j] = (f32x4){0.f, 0.f, 0.f, 0.f};

    const int wr = wid >> 1, wc = wid & 1;
    const int fm = lane & 15;
    // read slot' = (lane>>4) ^ ((row>>1)&3)
    const int rslot = (((lane >> 4) ^ ((lane >> 1) & 3)) & 3) << 3;
    int foffA[4], foffB[4];
#pragma unroll
    for (int i = 0; i < 4; ++i) {
        foffA[i] = (wr * 64 + i * 16 + fm) * 32 + rslot;
        foffB[i] = (wc * 64 + i * 16 + fm) * 32 + rslot;
    }

    for (int k0 = 0; k0 < K; k0 += 32) {
#pragma unroll
        for (int pp = 0; pp < NPA; ++pp)
#pragma unroll
            for (int i = 0; i < 2; ++i) {
                int c = wid * 2 + i;
                __builtin_amdgcn_global_load_lds(
                    (const AS1 void*)(A + pp * aPS + offA[i] + k0),
                    (AS3 void*)(As + pp * 4096 + c * 512), 16, 0, 0);
            }
#pragma unroll
        for (int pp = 0; pp < NPB; ++pp)
#pragma unroll
            for (int i = 0; i < 2; ++i) {
                int c = wid * 2 + i;
                __builtin_amdgcn_global_load_lds(
                    (const AS1 void*)(Bt + pp * bPS + offB[i] + k0),
                    (AS3 void*)(Bs + pp * 4096 + c * 512), 16, 0, 0);
            }
        __syncthreads();

        short8 af[NPA][4], bfr[NPB][4];
#pragma unroll
        for (int pp = 0; pp < NPA; ++pp)
#pragma unroll
            for (int i = 0; i < 4; ++i)
                af[pp][i] = *(const short8*)(As + pp * 4096 + foffA[i]);
#pragma unroll
        for (int pp = 0; pp < NPB; ++pp)
#pragma unroll
            for (int j = 0; j < 4; ++j)
                bfr[pp][j] = *(const short8*)(Bs + pp * 4096 + foffB[j]);

#pragma unroll
        for (int pp = 6 - NP; pp < 6; ++pp)
#pragma unroll
            for (int i = 0; i < 4; ++i)
#pragma unroll
                for (int j = 0; j < 4; ++j)
                    acc[i][j] = __builtin_amdgcn_mfma_f32_16x16x32_bf16(
                        af[PA[pp]][i], bfr[PB[pp]][j], acc[i][j], 0, 0, 0);
        __syncthreads();
    }

    // epilogue: C/D layout col = lane&15, row = (lane>>4)*4 + r
#pragma unroll
    for (int i = 0; i < 4; ++i) {
        int mbase = m0 + wr * 64 + i * 16 + ((lane >> 4) << 2);
#pragma unroll
        for (int j = 0; j < 4; ++j) {
            int n = n0 + wc * 64 + j * 16 + (lane & 15);
            float bv = bias[n];
#pragma unroll
            for (int rr = 0; rr < 4; ++rr) {
                int m = mbase + rr;
                float v = acc[i][j][rr] + bv;
                if (LRELU) v = (v >= 0.f) ? v : NEG_SLOPE * v;
                size_t o = (size_t)m * N + n;
                if (SPLITOUT) {
                    bf16 h, mm, ll;
                    split3v(v, h, mm, ll);
                    Cp[o] = h;
                    Cp[cPS + o] = mm;
                    Cp[2 * cPS + o] = ll;
                } else {
                    if (resid) v += resid[o];
                    C[o] = v;
                }
            }
        }
    }
}

// ---------------------------------------------------------------------------
// Fused attention (f32 vector): per block one 64-row q-tile of one (b,h).
// scores = 8*Q.K^T (+causal mask), online softmax, O = P.V, split3 output.
// LDS: Qst [e][t], KPs: K as [e][s] then reused for P as [s][t], Vs [s][e].
// 256 thr: (ty=tid>>4, tx=tid&15) own rows ty*4+i (t), cols tx*4+j (s or e).
// Row stats reduced across the 16-lane tx-group via shfl_xor.
template <int CAUSAL>
__global__ __launch_bounds__(256)
void attn_fused(const float* __restrict__ qkv, bf16* __restrict__ outp,
                size_t planeStride) {
    int bh = blockIdx.y;
    int b = bh >> 4, h = bh & 15;
    int t0 = blockIdx.x << 6;
    __shared__ float Qst[64][68];
    __shared__ float KPs[64][68];
    __shared__ float Vs[64][68];
    const int tid = threadIdx.x;
    const int tx = tid & 15, ty = tid >> 4;
    const int lr = tid >> 4, le = (tid & 15) << 2;

    // load Q transposed: Qst[e][t]
    const float* qb = qkv + (size_t)(b * T_SEQ + t0) * QLD + h * HSZ;
#pragma unroll
    for (int r = 0; r < 4; ++r) {
        int row = lr + (r << 4);
        float4 qv = *reinterpret_cast<const float4*>(qb + (size_t)row * QLD + le);
        Qst[le + 0][row] = qv.x;
        Qst[le + 1][row] = qv.y;
        Qst[le + 2][row] = qv.z;
        Qst[le + 3][row] = qv.w;
    }

    float o[4][4] = {};
    float mrow[4] = {-INFINITY, -INFINITY, -INFINITY, -INFINITY};
    float lrow[4] = {};

    const int NT = CAUSAL ? (blockIdx.x + 1) : (T_SEQ / 64);
    for (int st = 0; st < NT; ++st) {
        int s0 = st << 6;
        const float* kb = qkv + 1024 + (size_t)(b * T_SEQ + s0) * QLD + h * HSZ;
        const float* vb = qkv + 2048 + (size_t)(b * T_SEQ + s0) * QLD + h * HSZ;
#pragma unroll
        for (int r = 0; r < 4; ++r) {
            int row = lr + (r << 4);
            float4 kv = *reinterpret_cast<const float4*>(kb + (size_t)row * QLD + le);
            KPs[le + 0][row] = kv.x;
            KPs[le + 1][row] = kv.y;
            KPs[le + 2][row] = kv.z;
            KPs[le + 3][row] = kv.w;
            float4 vv = *reinterpret_cast<const float4*>(vb + (size_t)row * QLD + le);
            *reinterpret_cast<float4*>(&Vs[row][le]) = vv;
        }
        __syncthreads();

        // S = 8 * Q.K^T  (4x4 per thread)
        float s[4][4] = {};
        for (int e = 0; e < 64; ++e) {
            float4 a = *reinterpret_cast<const float4*>(&Qst[e][ty << 2]);
            float4 bb = *reinterpret_cast<const float4*>(&KPs[e][tx << 2]);
            float av[4] = {a.x, a.y, a.z, a.w};
            float bv[4] = {bb.x, bb.y, bb.z, bb.w};
#pragma unroll
            for (int i = 0; i < 4; ++i)
#pragma unroll
                for (int j = 0; j < 4; ++j) s[i][j] += av[i] * bv[j];
        }
#pragma unroll
        for (int i = 0; i < 4; ++i)
#pragma unroll
            for (int j = 0; j < 4; ++j) {
                float v = 8.0f * s[i][j];
                if (CAUSAL) {
                    int scol = s0 + (tx << 2) + j;
                    int trow = t0 + (ty << 2) + i;
                    if (scol > trow) v = -INFINITY;
                }
                s[i][j] = v;
            }

        // online softmax update per row
#pragma unroll
        for (int i = 0; i < 4; ++i) {
            float rmax = fmaxf(fmaxf(s[i][0], s[i][1]), fmaxf(s[i][2], s[i][3]));
#pragma unroll
            for (int msk = 1; msk < 16; msk <<= 1)
                rmax = fmaxf(rmax, __shfl_xor(rmax, msk));
            float mn = fmaxf(mrow[i], rmax);
            float fsc = __expf(mrow[i] - mn);
            float rs = 0.f;
#pragma unroll
            for (int j = 0; j < 4; ++j) {
                float pv = __expf(s[i][j] - mn);
                s[i][j] = pv;
                rs += pv;
            }
#pragma unroll
            for (int msk = 1; msk < 16; msk <<= 1) rs += __shfl_xor(rs, msk);
            lrow[i] = lrow[i] * fsc + rs;
            mrow[i] = mn;
#pragma unroll
            for (int j = 0; j < 4; ++j) o[i][j] *= fsc;
        }
        __syncthreads();    // all waves done reading K before P overwrites

        // write P transposed into KPs: [s][t]
#pragma unroll
        for (int i = 0; i < 4; ++i)
#pragma unroll
            for (int j = 0; j < 4; ++j)
                KPs[(tx << 2) + j][(ty << 2) + i] = s[i][j];
        __syncthreads();

        // O += P.V
        for (int kk = 0; kk < 64; ++kk) {
            float4 a = *reinterpret_cast<const float4*>(&KPs[kk][ty << 2]);
            float4 bb = *reinterpret_cast<const float4*>(&Vs[kk][tx << 2]);
            float av[4] = {a.x, a.y, a.z, a.w};
            float bv[4] = {bb.x, bb.y, bb.z, bb.w};
#pragma unroll
            for (int i = 0; i < 4; ++i)
#pragma unroll
                for (int j = 0; j < 4; ++j) o[i][j] += av[i] * bv[j];
        }
        __syncthreads();    // done with Vs/KPs before next tile load
    }

    // epilogue: normalize + split3 store
#pragma unroll
    for (int i = 0; i < 4; ++i) {
        float inv = 1.f / lrow[i];
        size_t orow = (size_t)(b * T_SEQ + t0 + (ty << 2) + i) * DMODEL
                      + h * HSZ + (tx << 2);
#pragma unroll
        for (int j = 0; j < 4; ++j) {
            bf16 h_, m_, l_;
            split3v(o[i][j] * inv, h_, m_, l_);
            outp[orow + j] = h_;
            outp[planeStride + orow + j] = m_;
            outp[2 * planeStride + orow + j] = l_;
        }
    }
}

// ---------------------------------------------------------------------------
extern "C" void kernel_launch(void* const* d_in, const int* in_sizes, int n_in,
                              void* d_out, int out_size, void* d_ws, size_t ws_size,
                              hipStream_t stream) {
    const int*   idx = (const int*)  d_in[0];
    const float* tok = (const float*)d_in[1];
    const float* pos = (const float*)d_in[2];
    const float* Wq  = (const float*)d_in[3];
    const float* bq  = (const float*)d_in[4];
    const float* Wk  = (const float*)d_in[5];
    const float* bk  = (const float*)d_in[6];
    const float* Wv  = (const float*)d_in[7];
    const float* bv  = (const float*)d_in[8];
    const float* Wo  = (const float*)d_in[9];
    const float* bo  = (const float*)d_in[10];
    const float* W1  = (const float*)d_in[11];
    const float* b1  = (const float*)d_in[12];
    const float* W2  = (const float*)d_in[13];
    const float* b2  = (const float*)d_in[14];
    const float* nw  = (const float*)d_in[15];
    const float* fnw = (const float*)d_in[16];
    const float* Wf  = (const float*)d_in[17];
    const float* bf  = (const float*)d_in[18];
    float* out = (float*)d_out;

    const size_t SZ   = (size_t)BT * DMODEL;    // 4M
    const size_t HSZF = (size_t)BT * DFF;       // 16M

    char* w = (char*)d_ws;
    auto alloc = [&](size_t bytes) {
        char* p = w;
        w += (bytes + 255) & ~(size_t)255;
        return p;
    };
    float* x    = (float*)alloc(SZ * 4);
    float* xo   = (float*)alloc(SZ * 4);
    bf16*  xnp  = (bf16*) alloc(SZ * 2 * 3);
    float* qkv  = (float*)alloc((size_t)BT * QLD * 4);
    bf16*  aop  = (bf16*) alloc(SZ * 2 * 3);
    bf16*  hbp  = (bf16*) alloc(HSZF * 2 * 3);                // ffn hidden planes
    // per-layer weight planes (reused); wf planes union on top
    char*  wreg = alloc(132ull * 1024 * 1024);
    bf16*  qkvTp = (bf16*)wreg;                               // 3 x 3072x1024
    bf16*  woTp  = qkvTp + 3ull * QLD * DMODEL;               // 3 x 1024x1024
    bf16*  w1Tp  = woTp  + 3ull * DMODEL * DMODEL;            // 3 x 4096x1024
    bf16*  w2Tp  = w1Tp  + 3ull * DFF * DMODEL;               // 3 x 1024x4096
    bf16*  wfp   = (bf16*)wreg;                               // 2 x 32000x1024
    float* catb  = (float*)alloc((size_t)NLAYER * QLD * 4);

    cat_bias<<<(NLAYER * QLD) / 256, 256, 0, stream>>>(bq, bk, bv, catb);
    embed_kernel<<<BT, 256, 0, stream>>>(idx, tok, pos, x);

    for (int l = 0; l < NLAYER; ++l) {
        const float* nwl = nw + (size_t)l * DMODEL;
        const float* catbl = catb + (size_t)l * QLD;
        const float* bol = bo + (size_t)l * DMODEL;
        const float* b1l = b1 + (size_t)l * DFF;
        const float* b2l = b2 + (size_t)l * DMODEL;

        // split this layer's weights into transposed bf16 planes
        {
            long izs = (long)DMODEL * HSZ;
            long ozi = (long)HSZ * DMODEL;
            size_t ps = (size_t)QLD * DMODEL;
            dim3 g(HSZ / 32, DMODEL / 32, NHEAD);
            const float* Wql = Wq + (size_t)l * NHEAD * DMODEL * HSZ;
            const float* Wkl = Wk + (size_t)l * NHEAD * DMODEL * HSZ;
            const float* Wvl = Wv + (size_t)l * NHEAD * DMODEL * HSZ;
            transpose_split<<<g, 256, 0, stream>>>(Wql, qkvTp,                 ps, 3, DMODEL, HSZ, izs, ozi);
            transpose_split<<<g, 256, 0, stream>>>(Wkl, qkvTp + 1024ul * 1024, ps, 3, DMODEL, HSZ, izs, ozi);
            transpose_split<<<g, 256, 0, stream>>>(Wvl, qkvTp + 2048ul * 1024, ps, 3, DMODEL, HSZ, izs, ozi);
            transpose_split<<<dim3(DMODEL / 32, DMODEL / 32, 1), 256, 0, stream>>>(
                Wo + (size_t)l * DMODEL * DMODEL, woTp, (size_t)DMODEL * DMODEL, 3, DMODEL, DMODEL, 0, 0);
            transpose_split<<<dim3(DFF / 32, DMODEL / 32, 1), 256, 0, stream>>>(
                W1 + (size_t)l * DMODEL * DFF, w1Tp, (size_t)DFF * DMODEL, 3, DMODEL, DFF, 0, 0);
            transpose_split<<<dim3(DMODEL / 32, DFF / 32, 1), 256, 0, stream>>>(
                W2 + (size_t)l * DMODEL * DFF, w2Tp, (size_t)DMODEL * DFF, 3, DFF, DMODEL, 0, 0);
        }

        auto attn = [&](const float* resid, float* outp, int causal) {
            // xnp holds rms-normed input planes
            gemm_ms<6, false, false><<<dim3((BT / 128) * (QLD / 128)), 256, 0, stream>>>(
                xnp, SZ, qkvTp, (size_t)QLD * DMODEL, catbl, nullptr,
                qkv, nullptr, 0, QLD, DMODEL);
            if (causal)
                attn_fused<1><<<dim3(T_SEQ / 64, BATCH * NHEAD), 256, 0, stream>>>(qkv, aop, SZ);
            else
                attn_fused<0><<<dim3(T_SEQ / 64, BATCH * NHEAD), 256, 0, stream>>>(qkv, aop, SZ);
            gemm_ms<6, false, false><<<dim3((BT / 128) * (DMODEL / 128)), 256, 0, stream>>>(
                aop, SZ, woTp, (size_t)DMODEL * DMODEL, bol, resid,
                outp, nullptr, 0, DMODEL, DMODEL);
        };

        // x_out1 = x + attn(rms(x), unmasked)
        rms_split<<<BT, 256, 0, stream>>>(x, nwl, xnp, SZ);
        attn(x, xo, 0);
        // x_out2 = x + ffn(rms(x_out1))      (residual from ORIGINAL x)
        rms_split<<<BT, 256, 0, stream>>>(xo, nwl, xnp, SZ);
        gemm_ms<6, true, true><<<dim3((BT / 128) * (DFF / 128)), 256, 0, stream>>>(
            xnp, SZ, w1Tp, (size_t)DFF * DMODEL, b1l, nullptr,
            nullptr, hbp, HSZF, DFF, DMODEL);
        gemm_ms<6, false, false><<<dim3((BT / 128) * (DMODEL / 128)), 256, 0, stream>>>(
            hbp, HSZF, w2Tp, (size_t)DMODEL * DFF, b2l, x,
            xo, nullptr, 0, DMODEL, DFF);
        // x = x_out2 + attn(rms(x_out2), masked)
        rms_split<<<BT, 256, 0, stream>>>(xo, nwl, xnp, SZ);
        attn(xo, x, 1);
    }

    // final: logits = rms(x, fnw) @ Wf + bf   (3-pass split)
    rms_split<<<BT, 256, 0, stream>>>(x, fnw, xnp, SZ);
    transpose_split<<<dim3(VOCAB / 32, DMODEL / 32, 1), 256, 0, stream>>>(
        Wf, wfp, (size_t)VOCAB * DMODEL, 2, DMODEL, VOCAB, 0, 0);
    gemm_ms<3, false, false><<<dim3((BT / 128) * (VOCAB / 128)), 256, 0, stream>>>(
        xnp, SZ, wfp, (size_t)VOCAB * DMODEL, bf, nullptr,
        out, nullptr, 0, VOCAB, DMODEL);
}

// Round 6
// 12453.468 us; speedup vs baseline: 2.0218x; 1.0380x over previous
//
#include <hip/hip_runtime.h>
#include <hip/hip_bf16.h>
#include <cstdint>
#include <cstddef>

#define T_SEQ   512
#define BATCH   8
#define BT      4096
#define DMODEL  1024
#define NHEAD   16
#define HSZ     64
#define NLAYER  8
#define DFF     4096
#define VOCAB   32000
#define EPS     1e-6f
#define NEG_SLOPE 0.1f
#define QLD     3072    // fused qkv row stride

typedef __attribute__((ext_vector_type(8))) short short8;
typedef __attribute__((ext_vector_type(4))) float f32x4;
typedef __hip_bfloat16 bf16;

#define AS1 __attribute__((address_space(1)))
#define AS3 __attribute__((address_space(3)))

// ---------------------------------------------------------------------------
__global__ void embed_kernel(const int* __restrict__ idx,
                             const float* __restrict__ tok,
                             const float* __restrict__ pos,
                             float* __restrict__ x) {
    int bt  = blockIdx.x;
    int tid = threadIdx.x;
    int token = idx[bt];
    int t = bt & (T_SEQ - 1);
    float4 a = reinterpret_cast<const float4*>(tok + (size_t)token * DMODEL)[tid];
    float4 p = reinterpret_cast<const float4*>(pos + (size_t)t * DMODEL)[tid];
    reinterpret_cast<float4*>(x + (size_t)bt * DMODEL)[tid] =
        make_float4(a.x + p.x, a.y + p.y, a.z + p.z, a.w + p.w);
}

// ---------------------------------------------------------------------------
// exact 3-way bf16 split of an f32 value (x == h + m + l exactly)
__device__ __forceinline__ void split3v(float v, bf16& h, bf16& m, bf16& l) {
    h = __float2bfloat16(v);
    float r1 = v - __bfloat162float(h);
    m = __float2bfloat16(r1);
    float r2 = r1 - __bfloat162float(m);
    l = __float2bfloat16(r2);
}

// ---------------------------------------------------------------------------
// rmsnorm f32 -> 3 bf16 planes
__global__ void rms_split(const float* __restrict__ x,
                          const float* __restrict__ w,
                          bf16* __restrict__ out, size_t planeStride) {
    int row = blockIdx.x;
    int tid = threadIdx.x;
    float4 v = reinterpret_cast<const float4*>(x + (size_t)row * DMODEL)[tid];
    float ss = v.x * v.x + v.y * v.y + v.z * v.z + v.w * v.w;
#pragma unroll
    for (int off = 32; off > 0; off >>= 1) ss += __shfl_xor(ss, off);
    __shared__ float wsum[4];
    if ((tid & 63) == 0) wsum[tid >> 6] = ss;
    __syncthreads();
    float tot = wsum[0] + wsum[1] + wsum[2] + wsum[3];
    float scale = rsqrtf(tot * (1.0f / DMODEL) + EPS);
    float4 wv = reinterpret_cast<const float4*>(w)[tid];
    float o[4] = {v.x * scale * wv.x, v.y * scale * wv.y,
                  v.z * scale * wv.z, v.w * scale * wv.w};
    size_t base = (size_t)row * DMODEL + tid * 4;
#pragma unroll
    for (int j = 0; j < 4; ++j) {
        bf16 h, m, l;
        split3v(o[j], h, m, l);
        out[base + j] = h;
        out[planeStride + base + j] = m;
        out[2 * planeStride + base + j] = l;
    }
}

// ---------------------------------------------------------------------------
// Tiled transpose + split: in (R,C) f32 -> out (C,R) bf16 x nPlanes
__global__ __launch_bounds__(256)
void transpose_split(const float* __restrict__ in, bf16* __restrict__ out,
                     size_t planeStride, int nPlanes, int R, int C,
                     long izs, long ozi) {
    int z = blockIdx.z;
    in  += (size_t)z * izs;
    out += (size_t)z * ozi;
    __shared__ float tile[32][33];
    int r0 = blockIdx.y << 5, c0 = blockIdx.x << 5;
    int tx = threadIdx.x & 31, ty = threadIdx.x >> 5;
#pragma unroll
    for (int i = 0; i < 4; ++i) {
        int r = ty + (i << 3);
        tile[r][tx] = in[(size_t)(r0 + r) * C + c0 + tx];
    }
    __syncthreads();
#pragma unroll
    for (int i = 0; i < 4; ++i) {
        int c = ty + (i << 3);
        float v = tile[tx][c];
        size_t o = (size_t)(c0 + c) * R + r0 + tx;
        bf16 h = __float2bfloat16(v);
        out[o] = h;
        if (nPlanes > 1) {
            float r1 = v - __bfloat162float(h);
            bf16 m = __float2bfloat16(r1);
            out[planeStride + o] = m;
            if (nPlanes > 2) {
                float r2 = r1 - __bfloat162float(m);
                out[2 * planeStride + o] = __float2bfloat16(r2);
            }
        }
    }
}

// concat per-layer qkv bias into (L, 3072) f32
__global__ void cat_bias(const float* __restrict__ bq, const float* __restrict__ bk,
                         const float* __restrict__ bv, float* __restrict__ cb) {
    int i = blockIdx.x * 256 + threadIdx.x;
    int l = i / QLD, r = i - l * QLD;
    const float* src = (r < 1024) ? bq : ((r < 2048) ? bk : bv);
    cb[i] = src[l * 1024 + (r & 1023)];
}

// ---------------------------------------------------------------------------
// Merged-pass split-precision MFMA GEMM, 2-phase double-buffered (T3 minimal).
// C = sum_p A[PA[p]] @ B[PB[p]]^T (+bias, lrelu, resid).
// 512 threads / 8 waves (wave grid 2m x 4n, per-wave 64x32 out, acc 4x2).
// Per K-step: STAGE(next tile, other buffer) issued FIRST, then ds_read+MFMA
// on current buffer, then one __syncthreads (vmcnt drain hidden under MFMA).
// LDS: NP=6 -> 2x(3+3)x8KB = 96KB (1 block/CU); NP=3 -> 64KB (2 blocks/CU).
// LDS 16B-slot XOR swizzle (key (row>>1)&3), pre-swizzled on global source.
// Grid 1D, M=4096 fixed (32 m-blocks): XCD-chunk swizzle, m-fastest.
template <int NP, bool LRELU, bool SPLITOUT>
__global__ __launch_bounds__(512, 2)
void gemm_ms(const bf16* __restrict__ A, size_t aPS,
             const bf16* __restrict__ Bt, size_t bPS,
             const float* __restrict__ bias,
             const float* __restrict__ resid,
             float* __restrict__ C, bf16* __restrict__ Cp, size_t cPS,
             int N, int K) {
    constexpr int NPA = (NP == 6) ? 3 : 2;
    constexpr int NPB = (NP == 6) ? 3 : 2;
    constexpr int PA[6] = {1, 0, 2, 0, 1, 0};   // mm,hl,lh,hm,mh,hh
    constexpr int PB[6] = {1, 2, 0, 1, 0, 0};
    __shared__ bf16 As[2][NPA * 4096];    // per plane: 128 rows x 32 k
    __shared__ bf16 Bs[2][NPB * 4096];

    // XCD chunk swizzle (grid % 8 == 0), then m-fastest (nblk = sw>>5)
    int chunk = gridDim.x >> 3;
    int bid = blockIdx.x;
    int sw = (bid & 7) * chunk + (bid >> 3);
    int m0 = (sw & 31) << 7;
    int n0 = (sw >> 5) << 7;

    const int tid  = threadIdx.x;
    const int lane = tid & 63;
    const int wid  = tid >> 6;

    // staging: thread t -> row t>>2 (0..127), 16B k-slot (t&3), XOR-preswizzled
    const int ssk = (((tid & 3) ^ ((tid >> 3) & 3)) << 3);
    const size_t offA = (size_t)(m0 + (tid >> 2)) * K + ssk;
    const size_t offB = (size_t)(n0 + (tid >> 2)) * K + ssk;
    const int ldst = wid * 512;           // wave-uniform LDS elem base

    f32x4 acc[4][2];
#pragma unroll
    for (int i = 0; i < 4; ++i)
#pragma unroll
        for (int j = 0; j < 2; ++j) acc[i][j] = (f32x4){0.f, 0.f, 0.f, 0.f};

    const int wr = wid >> 2, wc = wid & 3;   // wave tile: rows wr*64, cols wc*32
    const int fm = lane & 15;
    const int rslot = (((lane >> 4) ^ ((lane >> 1) & 3)) & 3) << 3;
    int foffA[4], foffB[2];
#pragma unroll
    for (int i = 0; i < 4; ++i) foffA[i] = (wr * 64 + i * 16 + fm) * 32 + rslot;
#pragma unroll
    for (int j = 0; j < 2; ++j) foffB[j] = (wc * 32 + j * 16 + fm) * 32 + rslot;

    auto STAGE = [&](int buf, int k0) {
#pragma unroll
        for (int pp = 0; pp < NPA; ++pp)
            __builtin_amdgcn_global_load_lds(
                (const AS1 void*)(A + pp * aPS + offA + k0),
                (AS3 void*)(&As[buf][pp * 4096 + ldst]), 16, 0, 0);
#pragma unroll
        for (int pp = 0; pp < NPB; ++pp)
            __builtin_amdgcn_global_load_lds(
                (const AS1 void*)(Bt + pp * bPS + offB + k0),
                (AS3 void*)(&Bs[buf][pp * 4096 + ldst]), 16, 0, 0);
    };

    const int nt = K >> 5;
    STAGE(0, 0);
    __syncthreads();
    int cur = 0;
    for (int t = 0; t < nt; ++t) {
        if (t + 1 < nt) STAGE(cur ^ 1, (t + 1) << 5);

        short8 af[NPA][4], bfr[NPB][2];
#pragma unroll
        for (int pp = 0; pp < NPA; ++pp)
#pragma unroll
            for (int i = 0; i < 4; ++i)
                af[pp][i] = *(const short8*)(&As[cur][pp * 4096 + foffA[i]]);
#pragma unroll
        for (int pp = 0; pp < NPB; ++pp)
#pragma unroll
            for (int j = 0; j < 2; ++j)
                bfr[pp][j] = *(const short8*)(&Bs[cur][pp * 4096 + foffB[j]]);

#pragma unroll
        for (int pp = 6 - NP; pp < 6; ++pp)
#pragma unroll
            for (int i = 0; i < 4; ++i)
#pragma unroll
                for (int j = 0; j < 2; ++j)
                    acc[i][j] = __builtin_amdgcn_mfma_f32_16x16x32_bf16(
                        af[PA[pp]][i], bfr[PB[pp]][j], acc[i][j], 0, 0, 0);
        __syncthreads();    // drains vmcnt(0): next-tile staging (issued early)
        cur ^= 1;
    }

    // epilogue: C/D layout col = lane&15, row = (lane>>4)*4 + r
#pragma unroll
    for (int i = 0; i < 4; ++i) {
        int mbase = m0 + wr * 64 + i * 16 + ((lane >> 4) << 2);
#pragma unroll
        for (int j = 0; j < 2; ++j) {
            int n = n0 + wc * 32 + j * 16 + fm;
            float bv = bias[n];
#pragma unroll
            for (int rr = 0; rr < 4; ++rr) {
                int m = mbase + rr;
                float v = acc[i][j][rr] + bv;
                if (LRELU) v = (v >= 0.f) ? v : NEG_SLOPE * v;
                size_t o = (size_t)m * N + n;
                if (SPLITOUT) {
                    bf16 h, mm, ll;
                    split3v(v, h, mm, ll);
                    Cp[o] = h;
                    Cp[cPS + o] = mm;
                    Cp[2 * cPS + o] = ll;
                } else {
                    if (resid) v += resid[o];
                    C[o] = v;
                }
            }
        }
    }
}

// ---------------------------------------------------------------------------
// Fused attention (f32 vector): per block one 64-row q-tile of one (b,h).
template <int CAUSAL>
__global__ __launch_bounds__(256)
void attn_fused(const float* __restrict__ qkv, bf16* __restrict__ outp,
                size_t planeStride) {
    int bh = blockIdx.y;
    int b = bh >> 4, h = bh & 15;
    int t0 = blockIdx.x << 6;
    __shared__ float Qst[64][68];
    __shared__ float KPs[64][68];
    __shared__ float Vs[64][68];
    const int tid = threadIdx.x;
    const int tx = tid & 15, ty = tid >> 4;
    const int lr = tid >> 4, le = (tid & 15) << 2;

    const float* qb = qkv + (size_t)(b * T_SEQ + t0) * QLD + h * HSZ;
#pragma unroll
    for (int r = 0; r < 4; ++r) {
        int row = lr + (r << 4);
        float4 qv = *reinterpret_cast<const float4*>(qb + (size_t)row * QLD + le);
        Qst[le + 0][row] = qv.x;
        Qst[le + 1][row] = qv.y;
        Qst[le + 2][row] = qv.z;
        Qst[le + 3][row] = qv.w;
    }

    float o[4][4] = {};
    float mrow[4] = {-INFINITY, -INFINITY, -INFINITY, -INFINITY};
    float lrow[4] = {};

    const int NT = CAUSAL ? (blockIdx.x + 1) : (T_SEQ / 64);
    for (int st = 0; st < NT; ++st) {
        int s0 = st << 6;
        const float* kb = qkv + 1024 + (size_t)(b * T_SEQ + s0) * QLD + h * HSZ;
        const float* vb = qkv + 2048 + (size_t)(b * T_SEQ + s0) * QLD + h * HSZ;
#pragma unroll
        for (int r = 0; r < 4; ++r) {
            int row = lr + (r << 4);
            float4 kv = *reinterpret_cast<const float4*>(kb + (size_t)row * QLD + le);
            KPs[le + 0][row] = kv.x;
            KPs[le + 1][row] = kv.y;
            KPs[le + 2][row] = kv.z;
            KPs[le + 3][row] = kv.w;
            float4 vv = *reinterpret_cast<const float4*>(vb + (size_t)row * QLD + le);
            *reinterpret_cast<float4*>(&Vs[row][le]) = vv;
        }
        __syncthreads();

        float s[4][4] = {};
        for (int e = 0; e < 64; ++e) {
            float4 a = *reinterpret_cast<const float4*>(&Qst[e][ty << 2]);
            float4 bb = *reinterpret_cast<const float4*>(&KPs[e][tx << 2]);
            float av[4] = {a.x, a.y, a.z, a.w};
            float bv[4] = {bb.x, bb.y, bb.z, bb.w};
#pragma unroll
            for (int i = 0; i < 4; ++i)
#pragma unroll
                for (int j = 0; j < 4; ++j) s[i][j] += av[i] * bv[j];
        }
#pragma unroll
        for (int i = 0; i < 4; ++i)
#pragma unroll
            for (int j = 0; j < 4; ++j) {
                float v = 8.0f * s[i][j];
                if (CAUSAL) {
                    int scol = s0 + (tx << 2) + j;
                    int trow = t0 + (ty << 2) + i;
                    if (scol > trow) v = -INFINITY;
                }
                s[i][j] = v;
            }

#pragma unroll
        for (int i = 0; i < 4; ++i) {
            float rmax = fmaxf(fmaxf(s[i][0], s[i][1]), fmaxf(s[i][2], s[i][3]));
#pragma unroll
            for (int msk = 1; msk < 16; msk <<= 1)
                rmax = fmaxf(rmax, __shfl_xor(rmax, msk));
            float mn = fmaxf(mrow[i], rmax);
            float fsc = __expf(mrow[i] - mn);
            float rs = 0.f;
#pragma unroll
            for (int j = 0; j < 4; ++j) {
                float pv = __expf(s[i][j] - mn);
                s[i][j] = pv;
                rs += pv;
            }
#pragma unroll
            for (int msk = 1; msk < 16; msk <<= 1) rs += __shfl_xor(rs, msk);
            lrow[i] = lrow[i] * fsc + rs;
            mrow[i] = mn;
#pragma unroll
            for (int j = 0; j < 4; ++j) o[i][j] *= fsc;
        }
        __syncthreads();

#pragma unroll
        for (int i = 0; i < 4; ++i)
#pragma unroll
            for (int j = 0; j < 4; ++j)
                KPs[(tx << 2) + j][(ty << 2) + i] = s[i][j];
        __syncthreads();

        for (int kk = 0; kk < 64; ++kk) {
            float4 a = *reinterpret_cast<const float4*>(&KPs[kk][ty << 2]);
            float4 bb = *reinterpret_cast<const float4*>(&Vs[kk][tx << 2]);
            float av[4] = {a.x, a.y, a.z, a.w};
            float bv[4] = {bb.x, bb.y, bb.z, bb.w};
#pragma unroll
            for (int i = 0; i < 4; ++i)
#pragma unroll
                for (int j = 0; j < 4; ++j) o[i][j] += av[i] * bv[j];
        }
        __syncthreads();
    }

#pragma unroll
    for (int i = 0; i < 4; ++i) {
        float inv = 1.f / lrow[i];
        size_t orow = (size_t)(b * T_SEQ + t0 + (ty << 2) + i) * DMODEL
                      + h * HSZ + (tx << 2);
#pragma unroll
        for (int j = 0; j < 4; ++j) {
            bf16 h_, m_, l_;
            split3v(o[i][j] * inv, h_, m_, l_);
            outp[orow + j] = h_;
            outp[planeStride + orow + j] = m_;
            outp[2 * planeStride + orow + j] = l_;
        }
    }
}

// ---------------------------------------------------------------------------
extern "C" void kernel_launch(void* const* d_in, const int* in_sizes, int n_in,
                              void* d_out, int out_size, void* d_ws, size_t ws_size,
                              hipStream_t stream) {
    const int*   idx = (const int*)  d_in[0];
    const float* tok = (const float*)d_in[1];
    const float* pos = (const float*)d_in[2];
    const float* Wq  = (const float*)d_in[3];
    const float* bq  = (const float*)d_in[4];
    const float* Wk  = (const float*)d_in[5];
    const float* bk  = (const float*)d_in[6];
    const float* Wv  = (const float*)d_in[7];
    const float* bv  = (const float*)d_in[8];
    const float* Wo  = (const float*)d_in[9];
    const float* bo  = (const float*)d_in[10];
    const float* W1  = (const float*)d_in[11];
    const float* b1  = (const float*)d_in[12];
    const float* W2  = (const float*)d_in[13];
    const float* b2  = (const float*)d_in[14];
    const float* nw  = (const float*)d_in[15];
    const float* fnw = (const float*)d_in[16];
    const float* Wf  = (const float*)d_in[17];
    const float* bf  = (const float*)d_in[18];
    float* out = (float*)d_out;

    const size_t SZ   = (size_t)BT * DMODEL;    // 4M
    const size_t HSZF = (size_t)BT * DFF;       // 16M

    char* w = (char*)d_ws;
    auto alloc = [&](size_t bytes) {
        char* p = w;
        w += (bytes + 255) & ~(size_t)255;
        return p;
    };
    float* x    = (float*)alloc(SZ * 4);
    float* xo   = (float*)alloc(SZ * 4);
    bf16*  xnp  = (bf16*) alloc(SZ * 2 * 3);
    float* qkv  = (float*)alloc((size_t)BT * QLD * 4);
    bf16*  aop  = (bf16*) alloc(SZ * 2 * 3);
    bf16*  hbp  = (bf16*) alloc(HSZF * 2 * 3);                // ffn hidden planes
    char*  wreg = alloc(132ull * 1024 * 1024);
    bf16*  qkvTp = (bf16*)wreg;                               // 3 x 3072x1024
    bf16*  woTp  = qkvTp + 3ull * QLD * DMODEL;               // 3 x 1024x1024
    bf16*  w1Tp  = woTp  + 3ull * DMODEL * DMODEL;            // 3 x 4096x1024
    bf16*  w2Tp  = w1Tp  + 3ull * DFF * DMODEL;               // 3 x 1024x4096
    bf16*  wfp   = (bf16*)wreg;                               // 2 x 32000x1024
    float* catb  = (float*)alloc((size_t)NLAYER * QLD * 4);

    cat_bias<<<(NLAYER * QLD) / 256, 256, 0, stream>>>(bq, bk, bv, catb);
    embed_kernel<<<BT, 256, 0, stream>>>(idx, tok, pos, x);

    for (int l = 0; l < NLAYER; ++l) {
        const float* nwl = nw + (size_t)l * DMODEL;
        const float* catbl = catb + (size_t)l * QLD;
        const float* bol = bo + (size_t)l * DMODEL;
        const float* b1l = b1 + (size_t)l * DFF;
        const float* b2l = b2 + (size_t)l * DMODEL;

        // split this layer's weights into transposed bf16 planes
        {
            long izs = (long)DMODEL * HSZ;
            long ozi = (long)HSZ * DMODEL;
            size_t ps = (size_t)QLD * DMODEL;
            dim3 g(HSZ / 32, DMODEL / 32, NHEAD);
            const float* Wql = Wq + (size_t)l * NHEAD * DMODEL * HSZ;
            const float* Wkl = Wk + (size_t)l * NHEAD * DMODEL * HSZ;
            const float* Wvl = Wv + (size_t)l * NHEAD * DMODEL * HSZ;
            transpose_split<<<g, 256, 0, stream>>>(Wql, qkvTp,                 ps, 3, DMODEL, HSZ, izs, ozi);
            transpose_split<<<g, 256, 0, stream>>>(Wkl, qkvTp + 1024ul * 1024, ps, 3, DMODEL, HSZ, izs, ozi);
            transpose_split<<<g, 256, 0, stream>>>(Wvl, qkvTp + 2048ul * 1024, ps, 3, DMODEL, HSZ, izs, ozi);
            transpose_split<<<dim3(DMODEL / 32, DMODEL / 32, 1), 256, 0, stream>>>(
                Wo + (size_t)l * DMODEL * DMODEL, woTp, (size_t)DMODEL * DMODEL, 3, DMODEL, DMODEL, 0, 0);
            transpose_split<<<dim3(DFF / 32, DMODEL / 32, 1), 256, 0, stream>>>(
                W1 + (size_t)l * DMODEL * DFF, w1Tp, (size_t)DFF * DMODEL, 3, DMODEL, DFF, 0, 0);
            transpose_split<<<dim3(DMODEL / 32, DFF / 32, 1), 256, 0, stream>>>(
                W2 + (size_t)l * DMODEL * DFF, w2Tp, (size_t)DMODEL * DFF, 3, DFF, DMODEL, 0, 0);
        }

        auto attn = [&](const float* resid, float* outp, int causal) {
            gemm_ms<6, false, false><<<dim3((BT / 128) * (QLD / 128)), 512, 0, stream>>>(
                xnp, SZ, qkvTp, (size_t)QLD * DMODEL, catbl, nullptr,
                qkv, nullptr, 0, QLD, DMODEL);
            if (causal)
                attn_fused<1><<<dim3(T_SEQ / 64, BATCH * NHEAD), 256, 0, stream>>>(qkv, aop, SZ);
            else
                attn_fused<0><<<dim3(T_SEQ / 64, BATCH * NHEAD), 256, 0, stream>>>(qkv, aop, SZ);
            gemm_ms<6, false, false><<<dim3((BT / 128) * (DMODEL / 128)), 512, 0, stream>>>(
                aop, SZ, woTp, (size_t)DMODEL * DMODEL, bol, resid,
                outp, nullptr, 0, DMODEL, DMODEL);
        };

        // x_out1 = x + attn(rms(x), unmasked)
        rms_split<<<BT, 256, 0, stream>>>(x, nwl, xnp, SZ);
        attn(x, xo, 0);
        // x_out2 = x + ffn(rms(x_out1))      (residual from ORIGINAL x)
        rms_split<<<BT, 256, 0, stream>>>(xo, nwl, xnp, SZ);
        gemm_ms<6, true, true><<<dim3((BT / 128) * (DFF / 128)), 512, 0, stream>>>(
            xnp, SZ, w1Tp, (size_t)DFF * DMODEL, b1l, nullptr,
            nullptr, hbp, HSZF, DFF, DMODEL);
        gemm_ms<6, false, false><<<dim3((BT / 128) * (DMODEL / 128)), 512, 0, stream>>>(
            hbp, HSZF, w2Tp, (size_t)DMODEL * DFF, b2l, x,
            xo, nullptr, 0, DMODEL, DFF);
        // x = x_out2 + attn(rms(x_out2), masked)
        rms_split<<<BT, 256, 0, stream>>>(xo, nwl, xnp, SZ);
        attn(xo, x, 1);
    }

    // final: logits = rms(x, fnw) @ Wf + bf   (3-pass split)
    rms_split<<<BT, 256, 0, stream>>>(x, fnw, xnp, SZ);
    transpose_split<<<dim3(VOCAB / 32, DMODEL / 32, 1), 256, 0, stream>>>(
        Wf, wfp, (size_t)VOCAB * DMODEL, 2, DMODEL, VOCAB, 0, 0);
    gemm_ms<3, false, false><<<dim3((BT / 128) * (VOCAB / 128)), 512, 0, stream>>>(
        xnp, SZ, wfp, (size_t)VOCAB * DMODEL, bf, nullptr,
        out, nullptr, 0, VOCAB, DMODEL);
}

// Round 7
// 11675.869 us; speedup vs baseline: 2.1564x; 1.0666x over previous
//
#include <hip/hip_runtime.h>
#include <hip/hip_bf16.h>
#include <cstdint>
#include <cstddef>

#define T_SEQ   512
#define BATCH   8
#define BT      4096
#define DMODEL  1024
#define NHEAD   16
#define HSZ     64
#define NLAYER  8
#define DFF     4096
#define VOCAB   32000
#define EPS     1e-6f
#define NEG_SLOPE 0.1f
#define QLD     3072    // fused qkv row stride

typedef __attribute__((ext_vector_type(8))) short short8;
typedef __attribute__((ext_vector_type(4))) float f32x4;
typedef __hip_bfloat16 bf16;

#define AS1 __attribute__((address_space(1)))
#define AS3 __attribute__((address_space(3)))

// counted-vmcnt wait fused with barrier (T4): the N newest vmem ops (the
// just-issued prefetch) stay in flight across the barrier.
#define WAIT_BAR(N) asm volatile("s_waitcnt vmcnt(" #N ")\ns_barrier" ::: "memory")
#define LGKM_BAR()  asm volatile("s_waitcnt lgkmcnt(0)\ns_barrier" ::: "memory")

// ---------------------------------------------------------------------------
__global__ void embed_kernel(const int* __restrict__ idx,
                             const float* __restrict__ tok,
                             const float* __restrict__ pos,
                             float* __restrict__ x) {
    int bt  = blockIdx.x;
    int tid = threadIdx.x;
    int token = idx[bt];
    int t = bt & (T_SEQ - 1);
    float4 a = reinterpret_cast<const float4*>(tok + (size_t)token * DMODEL)[tid];
    float4 p = reinterpret_cast<const float4*>(pos + (size_t)t * DMODEL)[tid];
    reinterpret_cast<float4*>(x + (size_t)bt * DMODEL)[tid] =
        make_float4(a.x + p.x, a.y + p.y, a.z + p.z, a.w + p.w);
}

// ---------------------------------------------------------------------------
__device__ __forceinline__ void split3v(float v, bf16& h, bf16& m, bf16& l) {
    h = __float2bfloat16(v);
    float r1 = v - __bfloat162float(h);
    m = __float2bfloat16(r1);
    float r2 = r1 - __bfloat162float(m);
    l = __float2bfloat16(r2);
}

// ---------------------------------------------------------------------------
__global__ void rms_split(const float* __restrict__ x,
                          const float* __restrict__ w,
                          bf16* __restrict__ out, size_t planeStride) {
    int row = blockIdx.x;
    int tid = threadIdx.x;
    float4 v = reinterpret_cast<const float4*>(x + (size_t)row * DMODEL)[tid];
    float ss = v.x * v.x + v.y * v.y + v.z * v.z + v.w * v.w;
#pragma unroll
    for (int off = 32; off > 0; off >>= 1) ss += __shfl_xor(ss, off);
    __shared__ float wsum[4];
    if ((tid & 63) == 0) wsum[tid >> 6] = ss;
    __syncthreads();
    float tot = wsum[0] + wsum[1] + wsum[2] + wsum[3];
    float scale = rsqrtf(tot * (1.0f / DMODEL) + EPS);
    float4 wv = reinterpret_cast<const float4*>(w)[tid];
    float o[4] = {v.x * scale * wv.x, v.y * scale * wv.y,
                  v.z * scale * wv.z, v.w * scale * wv.w};
    size_t base = (size_t)row * DMODEL + tid * 4;
#pragma unroll
    for (int j = 0; j < 4; ++j) {
        bf16 h, m, l;
        split3v(o[j], h, m, l);
        out[base + j] = h;
        out[planeStride + base + j] = m;
        out[2 * planeStride + base + j] = l;
    }
}

// ---------------------------------------------------------------------------
__global__ __launch_bounds__(256)
void transpose_split(const float* __restrict__ in, bf16* __restrict__ out,
                     size_t planeStride, int nPlanes, int R, int C,
                     long izs, long ozi) {
    int z = blockIdx.z;
    in  += (size_t)z * izs;
    out += (size_t)z * ozi;
    __shared__ float tile[32][33];
    int r0 = blockIdx.y << 5, c0 = blockIdx.x << 5;
    int tx = threadIdx.x & 31, ty = threadIdx.x >> 5;
#pragma unroll
    for (int i = 0; i < 4; ++i) {
        int r = ty + (i << 3);
        tile[r][tx] = in[(size_t)(r0 + r) * C + c0 + tx];
    }
    __syncthreads();
#pragma unroll
    for (int i = 0; i < 4; ++i) {
        int c = ty + (i << 3);
        float v = tile[tx][c];
        size_t o = (size_t)(c0 + c) * R + r0 + tx;
        bf16 h = __float2bfloat16(v);
        out[o] = h;
        if (nPlanes > 1) {
            float r1 = v - __bfloat162float(h);
            bf16 m = __float2bfloat16(r1);
            out[planeStride + o] = m;
            if (nPlanes > 2) {
                float r2 = r1 - __bfloat162float(m);
                out[2 * planeStride + o] = __float2bfloat16(r2);
            }
        }
    }
}

// concat per-layer qkv bias into (L, 3072) f32
__global__ void cat_bias(const float* __restrict__ bq, const float* __restrict__ bk,
                         const float* __restrict__ bv, float* __restrict__ cb) {
    int i = blockIdx.x * 256 + threadIdx.x;
    int l = i / QLD, r = i - l * QLD;
    const float* src = (r < 1024) ? bq : ((r < 2048) ? bk : bv);
    cb[i] = src[l * 1024 + (r & 1023)];
}

// ---------------------------------------------------------------------------
// WIDE merged-pass split GEMM: block 256(m) x 128(n), 512 thr / 8 waves
// (wave grid 4m x 2n, per-wave 64x64, acc 4x4). Double-buffered LDS with
// counted-vmcnt prefetch (loads stay in flight across s_barrier).
// LDS: NP6 2*(48+24)KB = 144KB (1 blk/CU, 2 waves/SIMD); NP3 96KB.
// Used for QKV (N=3072), W1 (N=4096), vocab (N=32000, NP=3).
template <int NP, bool LRELU, bool SPLITOUT>
__global__ __launch_bounds__(512, 2)
void gemm_wide(const bf16* __restrict__ A, size_t aPS,
               const bf16* __restrict__ Bt, size_t bPS,
               const float* __restrict__ bias,
               const float* __restrict__ resid,
               float* __restrict__ C, bf16* __restrict__ Cp, size_t cPS,
               int N, int K) {
    constexpr int NPA = (NP == 6) ? 3 : 2;
    constexpr int NPB = (NP == 6) ? 3 : 2;
    constexpr int PA[6] = {1, 0, 2, 0, 1, 0};   // mm,hl,lh,hm,mh,hh
    constexpr int PB[6] = {1, 2, 0, 1, 0, 0};
    __shared__ bf16 As[2][NPA * 8192];    // 256 rows x 32 k per plane
    __shared__ bf16 Bs[2][NPB * 4096];    // 128 rows x 32 k per plane

    // XCD chunk swizzle (grid % 8 == 0), m-fastest (16 m-blocks of 256)
    int chunk = gridDim.x >> 3;
    int bid = blockIdx.x;
    int sw = (bid & 7) * chunk + (bid >> 3);
    int m0 = (sw & 15) << 8;
    int n0 = (sw >> 4) << 7;

    const int tid  = threadIdx.x;
    const int lane = tid & 63;
    const int wid  = tid >> 6;

    // staging: A chunks c=wid*2+i (16 x 1KB), B chunk c=wid (8 x 1KB);
    // lane -> row c*16+(lane>>2), 16B k-slot XOR-preswizzled on global side.
    const int ssk = (((lane & 3) ^ ((lane >> 3) & 3)) << 3);
    size_t offA[2];
#pragma unroll
    for (int i = 0; i < 2; ++i)
        offA[i] = (size_t)(m0 + (wid * 2 + i) * 16 + (lane >> 2)) * K + ssk;
    const size_t offB = (size_t)(n0 + wid * 16 + (lane >> 2)) * K + ssk;

    f32x4 acc[4][4];
#pragma unroll
    for (int i = 0; i < 4; ++i)
#pragma unroll
        for (int j = 0; j < 4; ++j) acc[i][j] = (f32x4){0.f, 0.f, 0.f, 0.f};

    const int wr = wid >> 1, wc = wid & 1;   // wave tile rows wr*64, cols wc*64
    const int fm = lane & 15;
    const int rslot = (((lane >> 4) ^ ((lane >> 1) & 3)) & 3) << 3;
    int foffA[4], foffB[4];
#pragma unroll
    for (int i = 0; i < 4; ++i) foffA[i] = (wr * 64 + i * 16 + fm) * 32 + rslot;
#pragma unroll
    for (int j = 0; j < 4; ++j) foffB[j] = (wc * 64 + j * 16 + fm) * 32 + rslot;

    auto STAGE = [&](int buf, int k0) {
#pragma unroll
        for (int pp = 0; pp < NPA; ++pp)
#pragma unroll
            for (int i = 0; i < 2; ++i)
                __builtin_amdgcn_global_load_lds(
                    (const AS1 void*)(A + pp * aPS + offA[i] + k0),
                    (AS3 void*)(&As[buf][pp * 8192 + (wid * 2 + i) * 512]), 16, 0, 0);
#pragma unroll
        for (int pp = 0; pp < NPB; ++pp)
            __builtin_amdgcn_global_load_lds(
                (const AS1 void*)(Bt + pp * bPS + offB + k0),
                (AS3 void*)(&Bs[buf][pp * 4096 + wid * 512]), 16, 0, 0);
    };

    const int nt = K >> 5;
    STAGE(0, 0);
    int cur = 0;
    for (int t = 0; t < nt; ++t) {
        if (t + 1 < nt) {
            STAGE(cur ^ 1, (t + 1) << 5);
            if constexpr (NP == 6) WAIT_BAR(9); else WAIT_BAR(6);
        } else {
            WAIT_BAR(0);
        }

        short8 af[NPA][4], bfr[NPB][4];
#pragma unroll
        for (int pp = 0; pp < NPA; ++pp)
#pragma unroll
            for (int i = 0; i < 4; ++i)
                af[pp][i] = *(const short8*)(&As[cur][pp * 8192 + foffA[i]]);
#pragma unroll
        for (int pp = 0; pp < NPB; ++pp)
#pragma unroll
            for (int j = 0; j < 4; ++j)
                bfr[pp][j] = *(const short8*)(&Bs[cur][pp * 4096 + foffB[j]]);

#pragma unroll
        for (int pp = 6 - NP; pp < 6; ++pp)
#pragma unroll
            for (int i = 0; i < 4; ++i)
#pragma unroll
                for (int j = 0; j < 4; ++j)
                    acc[i][j] = __builtin_amdgcn_mfma_f32_16x16x32_bf16(
                        af[PA[pp]][i], bfr[PB[pp]][j], acc[i][j], 0, 0, 0);
        LGKM_BAR();     // all waves done reading buf[cur] before t+1 overwrites
        cur ^= 1;
    }

    // epilogue: C/D layout col = lane&15, row = (lane>>4)*4 + rr
#pragma unroll
    for (int i = 0; i < 4; ++i) {
        int mbase = m0 + wr * 64 + i * 16 + ((lane >> 4) << 2);
#pragma unroll
        for (int j = 0; j < 4; ++j) {
            int n = n0 + wc * 64 + j * 16 + fm;
            float bv = bias[n];
#pragma unroll
            for (int rr = 0; rr < 4; ++rr) {
                int m = mbase + rr;
                float v = acc[i][j][rr] + bv;
                if (LRELU) v = (v >= 0.f) ? v : NEG_SLOPE * v;
                size_t o = (size_t)m * N + n;
                if (SPLITOUT) {
                    bf16 h, mm, ll;
                    split3v(v, h, mm, ll);
                    Cp[o] = h;
                    Cp[cPS + o] = mm;
                    Cp[2 * cPS + o] = ll;
                } else {
                    if (resid) v += resid[o];
                    C[o] = v;
                }
            }
        }
    }
}

// ---------------------------------------------------------------------------
// NARROW merged-pass split GEMM (128x128, 8 waves 2m x 4n, 64x32/wave) with
// counted-vmcnt. Used for N=1024 GEMMs (O-proj, W2) where grid = 256 exactly.
template <int NP, bool LRELU>
__global__ __launch_bounds__(512, 2)
void gemm_nar(const bf16* __restrict__ A, size_t aPS,
              const bf16* __restrict__ Bt, size_t bPS,
              const float* __restrict__ bias,
              const float* __restrict__ resid,
              float* __restrict__ C, int N, int K) {
    constexpr int NPA = (NP == 6) ? 3 : 2;
    constexpr int NPB = (NP == 6) ? 3 : 2;
    constexpr int PA[6] = {1, 0, 2, 0, 1, 0};
    constexpr int PB[6] = {1, 2, 0, 1, 0, 0};
    __shared__ bf16 As[2][NPA * 4096];
    __shared__ bf16 Bs[2][NPB * 4096];

    int chunk = gridDim.x >> 3;
    int bid = blockIdx.x;
    int sw = (bid & 7) * chunk + (bid >> 3);
    int m0 = (sw & 31) << 7;
    int n0 = (sw >> 5) << 7;

    const int tid  = threadIdx.x;
    const int lane = tid & 63;
    const int wid  = tid >> 6;

    const int ssk = (((tid & 3) ^ ((tid >> 3) & 3)) << 3);
    const size_t offA = (size_t)(m0 + (tid >> 2)) * K + ssk;
    const size_t offB = (size_t)(n0 + (tid >> 2)) * K + ssk;
    const int ldst = wid * 512;

    f32x4 acc[4][2];
#pragma unroll
    for (int i = 0; i < 4; ++i)
#pragma unroll
        for (int j = 0; j < 2; ++j) acc[i][j] = (f32x4){0.f, 0.f, 0.f, 0.f};

    const int wr = wid >> 2, wc = wid & 3;
    const int fm = lane & 15;
    const int rslot = (((lane >> 4) ^ ((lane >> 1) & 3)) & 3) << 3;
    int foffA[4], foffB[2];
#pragma unroll
    for (int i = 0; i < 4; ++i) foffA[i] = (wr * 64 + i * 16 + fm) * 32 + rslot;
#pragma unroll
    for (int j = 0; j < 2; ++j) foffB[j] = (wc * 32 + j * 16 + fm) * 32 + rslot;

    auto STAGE = [&](int buf, int k0) {
#pragma unroll
        for (int pp = 0; pp < NPA; ++pp)
            __builtin_amdgcn_global_load_lds(
                (const AS1 void*)(A + pp * aPS + offA + k0),
                (AS3 void*)(&As[buf][pp * 4096 + ldst]), 16, 0, 0);
#pragma unroll
        for (int pp = 0; pp < NPB; ++pp)
            __builtin_amdgcn_global_load_lds(
                (const AS1 void*)(Bt + pp * bPS + offB + k0),
                (AS3 void*)(&Bs[buf][pp * 4096 + ldst]), 16, 0, 0);
    };

    const int nt = K >> 5;
    STAGE(0, 0);
    int cur = 0;
    for (int t = 0; t < nt; ++t) {
        if (t + 1 < nt) {
            STAGE(cur ^ 1, (t + 1) << 5);
            if constexpr (NP == 6) WAIT_BAR(6); else WAIT_BAR(4);
        } else {
            WAIT_BAR(0);
        }

        short8 af[NPA][4], bfr[NPB][2];
#pragma unroll
        for (int pp = 0; pp < NPA; ++pp)
#pragma unroll
            for (int i = 0; i < 4; ++i)
                af[pp][i] = *(const short8*)(&As[cur][pp * 4096 + foffA[i]]);
#pragma unroll
        for (int pp = 0; pp < NPB; ++pp)
#pragma unroll
            for (int j = 0; j < 2; ++j)
                bfr[pp][j] = *(const short8*)(&Bs[cur][pp * 4096 + foffB[j]]);

#pragma unroll
        for (int pp = 6 - NP; pp < 6; ++pp)
#pragma unroll
            for (int i = 0; i < 4; ++i)
#pragma unroll
                for (int j = 0; j < 2; ++j)
                    acc[i][j] = __builtin_amdgcn_mfma_f32_16x16x32_bf16(
                        af[PA[pp]][i], bfr[PB[pp]][j], acc[i][j], 0, 0, 0);
        LGKM_BAR();
        cur ^= 1;
    }

#pragma unroll
    for (int i = 0; i < 4; ++i) {
        int mbase = m0 + wr * 64 + i * 16 + ((lane >> 4) << 2);
#pragma unroll
        for (int j = 0; j < 2; ++j) {
            int n = n0 + wc * 32 + j * 16 + fm;
            float bv = bias[n];
#pragma unroll
            for (int rr = 0; rr < 4; ++rr) {
                int m = mbase + rr;
                float v = acc[i][j][rr] + bv;
                if (LRELU) v = (v >= 0.f) ? v : NEG_SLOPE * v;
                size_t o = (size_t)m * N + n;
                if (resid) v += resid[o];
                C[o] = v;
            }
        }
    }
}

// ---------------------------------------------------------------------------
// Fused attention (f32 vector): per block one 64-row q-tile of one (b,h).
template <int CAUSAL>
__global__ __launch_bounds__(256)
void attn_fused(const float* __restrict__ qkv, bf16* __restrict__ outp,
                size_t planeStride) {
    int bh = blockIdx.y;
    int b = bh >> 4, h = bh & 15;
    int t0 = blockIdx.x << 6;
    __shared__ float Qst[64][68];
    __shared__ float KPs[64][68];
    __shared__ float Vs[64][68];
    const int tid = threadIdx.x;
    const int tx = tid & 15, ty = tid >> 4;
    const int lr = tid >> 4, le = (tid & 15) << 2;

    const float* qb = qkv + (size_t)(b * T_SEQ + t0) * QLD + h * HSZ;
#pragma unroll
    for (int r = 0; r < 4; ++r) {
        int row = lr + (r << 4);
        float4 qv = *reinterpret_cast<const float4*>(qb + (size_t)row * QLD + le);
        Qst[le + 0][row] = qv.x;
        Qst[le + 1][row] = qv.y;
        Qst[le + 2][row] = qv.z;
        Qst[le + 3][row] = qv.w;
    }

    float o[4][4] = {};
    float mrow[4] = {-INFINITY, -INFINITY, -INFINITY, -INFINITY};
    float lrow[4] = {};

    const int NT = CAUSAL ? (blockIdx.x + 1) : (T_SEQ / 64);
    for (int st = 0; st < NT; ++st) {
        int s0 = st << 6;
        const float* kb = qkv + 1024 + (size_t)(b * T_SEQ + s0) * QLD + h * HSZ;
        const float* vb = qkv + 2048 + (size_t)(b * T_SEQ + s0) * QLD + h * HSZ;
#pragma unroll
        for (int r = 0; r < 4; ++r) {
            int row = lr + (r << 4);
            float4 kv = *reinterpret_cast<const float4*>(kb + (size_t)row * QLD + le);
            KPs[le + 0][row] = kv.x;
            KPs[le + 1][row] = kv.y;
            KPs[le + 2][row] = kv.z;
            KPs[le + 3][row] = kv.w;
            float4 vv = *reinterpret_cast<const float4*>(vb + (size_t)row * QLD + le);
            *reinterpret_cast<float4*>(&Vs[row][le]) = vv;
        }
        __syncthreads();

        float s[4][4] = {};
        for (int e = 0; e < 64; ++e) {
            float4 a = *reinterpret_cast<const float4*>(&Qst[e][ty << 2]);
            float4 bb = *reinterpret_cast<const float4*>(&KPs[e][tx << 2]);
            float av[4] = {a.x, a.y, a.z, a.w};
            float bv[4] = {bb.x, bb.y, bb.z, bb.w};
#pragma unroll
            for (int i = 0; i < 4; ++i)
#pragma unroll
                for (int j = 0; j < 4; ++j) s[i][j] += av[i] * bv[j];
        }
#pragma unroll
        for (int i = 0; i < 4; ++i)
#pragma unroll
            for (int j = 0; j < 4; ++j) {
                float v = 8.0f * s[i][j];
                if (CAUSAL) {
                    int scol = s0 + (tx << 2) + j;
                    int trow = t0 + (ty << 2) + i;
                    if (scol > trow) v = -INFINITY;
                }
                s[i][j] = v;
            }

#pragma unroll
        for (int i = 0; i < 4; ++i) {
            float rmax = fmaxf(fmaxf(s[i][0], s[i][1]), fmaxf(s[i][2], s[i][3]));
#pragma unroll
            for (int msk = 1; msk < 16; msk <<= 1)
                rmax = fmaxf(rmax, __shfl_xor(rmax, msk));
            float mn = fmaxf(mrow[i], rmax);
            float fsc = __expf(mrow[i] - mn);
            float rs = 0.f;
#pragma unroll
            for (int j = 0; j < 4; ++j) {
                float pv = __expf(s[i][j] - mn);
                s[i][j] = pv;
                rs += pv;
            }
#pragma unroll
            for (int msk = 1; msk < 16; msk <<= 1) rs += __shfl_xor(rs, msk);
            lrow[i] = lrow[i] * fsc + rs;
            mrow[i] = mn;
#pragma unroll
            for (int j = 0; j < 4; ++j) o[i][j] *= fsc;
        }
        __syncthreads();

#pragma unroll
        for (int i = 0; i < 4; ++i)
#pragma unroll
            for (int j = 0; j < 4; ++j)
                KPs[(tx << 2) + j][(ty << 2) + i] = s[i][j];
        __syncthreads();

        for (int kk = 0; kk < 64; ++kk) {
            float4 a = *reinterpret_cast<const float4*>(&KPs[kk][ty << 2]);
            float4 bb = *reinterpret_cast<const float4*>(&Vs[kk][tx << 2]);
            float av[4] = {a.x, a.y, a.z, a.w};
            float bv[4] = {bb.x, bb.y, bb.z, bb.w};
#pragma unroll
            for (int i = 0; i < 4; ++i)
#pragma unroll
                for (int j = 0; j < 4; ++j) o[i][j] += av[i] * bv[j];
        }
        __syncthreads();
    }

#pragma unroll
    for (int i = 0; i < 4; ++i) {
        float inv = 1.f / lrow[i];
        size_t orow = (size_t)(b * T_SEQ + t0 + (ty << 2) + i) * DMODEL
                      + h * HSZ + (tx << 2);
#pragma unroll
        for (int j = 0; j < 4; ++j) {
            bf16 h_, m_, l_;
            split3v(o[i][j] * inv, h_, m_, l_);
            outp[orow + j] = h_;
            outp[planeStride + orow + j] = m_;
            outp[2 * planeStride + orow + j] = l_;
        }
    }
}

// ---------------------------------------------------------------------------
extern "C" void kernel_launch(void* const* d_in, const int* in_sizes, int n_in,
                              void* d_out, int out_size, void* d_ws, size_t ws_size,
                              hipStream_t stream) {
    const int*   idx = (const int*)  d_in[0];
    const float* tok = (const float*)d_in[1];
    const float* pos = (const float*)d_in[2];
    const float* Wq  = (const float*)d_in[3];
    const float* bq  = (const float*)d_in[4];
    const float* Wk  = (const float*)d_in[5];
    const float* bk  = (const float*)d_in[6];
    const float* Wv  = (const float*)d_in[7];
    const float* bv  = (const float*)d_in[8];
    const float* Wo  = (const float*)d_in[9];
    const float* bo  = (const float*)d_in[10];
    const float* W1  = (const float*)d_in[11];
    const float* b1  = (const float*)d_in[12];
    const float* W2  = (const float*)d_in[13];
    const float* b2  = (const float*)d_in[14];
    const float* nw  = (const float*)d_in[15];
    const float* fnw = (const float*)d_in[16];
    const float* Wf  = (const float*)d_in[17];
    const float* bf  = (const float*)d_in[18];
    float* out = (float*)d_out;

    const size_t SZ   = (size_t)BT * DMODEL;    // 4M
    const size_t HSZF = (size_t)BT * DFF;       // 16M

    char* w = (char*)d_ws;
    auto alloc = [&](size_t bytes) {
        char* p = w;
        w += (bytes + 255) & ~(size_t)255;
        return p;
    };
    float* x    = (float*)alloc(SZ * 4);
    float* xo   = (float*)alloc(SZ * 4);
    bf16*  xnp  = (bf16*) alloc(SZ * 2 * 3);
    float* qkv  = (float*)alloc((size_t)BT * QLD * 4);
    bf16*  aop  = (bf16*) alloc(SZ * 2 * 3);
    bf16*  hbp  = (bf16*) alloc(HSZF * 2 * 3);                // ffn hidden planes
    char*  wreg = alloc(132ull * 1024 * 1024);
    bf16*  qkvTp = (bf16*)wreg;                               // 3 x 3072x1024
    bf16*  woTp  = qkvTp + 3ull * QLD * DMODEL;               // 3 x 1024x1024
    bf16*  w1Tp  = woTp  + 3ull * DMODEL * DMODEL;            // 3 x 4096x1024
    bf16*  w2Tp  = w1Tp  + 3ull * DFF * DMODEL;               // 3 x 1024x4096
    bf16*  wfp   = (bf16*)wreg;                               // 2 x 32000x1024
    float* catb  = (float*)alloc((size_t)NLAYER * QLD * 4);

    cat_bias<<<(NLAYER * QLD) / 256, 256, 0, stream>>>(bq, bk, bv, catb);
    embed_kernel<<<BT, 256, 0, stream>>>(idx, tok, pos, x);

    for (int l = 0; l < NLAYER; ++l) {
        const float* nwl = nw + (size_t)l * DMODEL;
        const float* catbl = catb + (size_t)l * QLD;
        const float* bol = bo + (size_t)l * DMODEL;
        const float* b1l = b1 + (size_t)l * DFF;
        const float* b2l = b2 + (size_t)l * DMODEL;

        // split this layer's weights into transposed bf16 planes
        {
            long izs = (long)DMODEL * HSZ;
            long ozi = (long)HSZ * DMODEL;
            size_t ps = (size_t)QLD * DMODEL;
            dim3 g(HSZ / 32, DMODEL / 32, NHEAD);
            const float* Wql = Wq + (size_t)l * NHEAD * DMODEL * HSZ;
            const float* Wkl = Wk + (size_t)l * NHEAD * DMODEL * HSZ;
            const float* Wvl = Wv + (size_t)l * NHEAD * DMODEL * HSZ;
            transpose_split<<<g, 256, 0, stream>>>(Wql, qkvTp,                 ps, 3, DMODEL, HSZ, izs, ozi);
            transpose_split<<<g, 256, 0, stream>>>(Wkl, qkvTp + 1024ul * 1024, ps, 3, DMODEL, HSZ, izs, ozi);
            transpose_split<<<g, 256, 0, stream>>>(Wvl, qkvTp + 2048ul * 1024, ps, 3, DMODEL, HSZ, izs, ozi);
            transpose_split<<<dim3(DMODEL / 32, DMODEL / 32, 1), 256, 0, stream>>>(
                Wo + (size_t)l * DMODEL * DMODEL, woTp, (size_t)DMODEL * DMODEL, 3, DMODEL, DMODEL, 0, 0);
            transpose_split<<<dim3(DFF / 32, DMODEL / 32, 1), 256, 0, stream>>>(
                W1 + (size_t)l * DMODEL * DFF, w1Tp, (size_t)DFF * DMODEL, 3, DMODEL, DFF, 0, 0);
            transpose_split<<<dim3(DMODEL / 32, DFF / 32, 1), 256, 0, stream>>>(
                W2 + (size_t)l * DMODEL * DFF, w2Tp, (size_t)DMODEL * DFF, 3, DFF, DMODEL, 0, 0);
        }

        auto attn = [&](const float* resid, float* outp, int causal) {
            gemm_wide<6, false, false><<<dim3((BT / 256) * (QLD / 128)), 512, 0, stream>>>(
                xnp, SZ, qkvTp, (size_t)QLD * DMODEL, catbl, nullptr,
                qkv, nullptr, 0, QLD, DMODEL);
            if (causal)
                attn_fused<1><<<dim3(T_SEQ / 64, BATCH * NHEAD), 256, 0, stream>>>(qkv, aop, SZ);
            else
                attn_fused<0><<<dim3(T_SEQ / 64, BATCH * NHEAD), 256, 0, stream>>>(qkv, aop, SZ);
            gemm_nar<6, false><<<dim3((BT / 128) * (DMODEL / 128)), 512, 0, stream>>>(
                aop, SZ, woTp, (size_t)DMODEL * DMODEL, bol, resid,
                outp, DMODEL, DMODEL);
        };

        // x_out1 = x + attn(rms(x), unmasked)
        rms_split<<<BT, 256, 0, stream>>>(x, nwl, xnp, SZ);
        attn(x, xo, 0);
        // x_out2 = x + ffn(rms(x_out1))      (residual from ORIGINAL x)
        rms_split<<<BT, 256, 0, stream>>>(xo, nwl, xnp, SZ);
        gemm_wide<6, true, true><<<dim3((BT / 256) * (DFF / 128)), 512, 0, stream>>>(
            xnp, SZ, w1Tp, (size_t)DFF * DMODEL, b1l, nullptr,
            nullptr, hbp, HSZF, DFF, DMODEL);
        gemm_nar<6, false><<<dim3((BT / 128) * (DMODEL / 128)), 512, 0, stream>>>(
            hbp, HSZF, w2Tp, (size_t)DMODEL * DFF, b2l, x,
            xo, DMODEL, DFF);
        // x = x_out2 + attn(rms(x_out2), masked)
        rms_split<<<BT, 256, 0, stream>>>(xo, nwl, xnp, SZ);
        attn(xo, x, 1);
    }

    // final: logits = rms(x, fnw) @ Wf + bf   (3-pass split, 2 planes)
    rms_split<<<BT, 256, 0, stream>>>(x, fnw, xnp, SZ);
    transpose_split<<<dim3(VOCAB / 32, DMODEL / 32, 1), 256, 0, stream>>>(
        Wf, wfp, (size_t)VOCAB * DMODEL, 2, DMODEL, VOCAB, 0, 0);
    gemm_wide<3, false, false><<<dim3((BT / 256) * (VOCAB / 128)), 512, 0, stream>>>(
        xnp, SZ, wfp, (size_t)VOCAB * DMODEL, bf, nullptr,
        out, nullptr, 0, VOCAB, DMODEL);
}